// Round 1
// baseline (2355.426 us; speedup 1.0000x reference)
//
#include <hip/hip_runtime.h>
#include <math.h>

// Problem constants
#define NSEQ   1024
#define DMODEL 1024
#define BATCH  4
#define NHEAD  16
#define DHEAD  64
#define ZTOT   64               // NHEAD*BATCH
#define NROWS  4096             // BATCH*NSEQ
#define NEG_BIG (-4294967295.0f) // -2^32 + 1, from the reference

// ---------------------------------------------------------------------------
// GEMM: Y = act( (X @ W^T) * scale + bias )
// X: [4096, 1024] row-major, W: [1024, 1024] row-major (torch Linear weight)
// headmajor=1: write into head-major [Z=64, N=1024, DH=64] layout (to_heads)
// ---------------------------------------------------------------------------
__launch_bounds__(256)
__global__ void gemm_xwt(const float* __restrict__ X, const float* __restrict__ W,
                         const float* __restrict__ bias, float* __restrict__ Y,
                         float scale, int relu, int headmajor)
{
    __shared__ float As[16][65];   // [k][m] for 64-row tile
    __shared__ float Bs[16][65];
    const int bx = blockIdx.x;     // col tile (16 tiles of 64)
    const int by = blockIdx.y;     // row tile (64 tiles of 64)
    const int tid = threadIdx.x;
    const int tx = tid & 15;       // 0..15
    const int ty = tid >> 4;       // 0..15
    const int row0 = by * 64, col0 = bx * 64;

    float acc[4][4] = {};
    for (int k0 = 0; k0 < DMODEL; k0 += 16) {
        #pragma unroll
        for (int i = 0; i < 4; i++) {
            int idx = tid + i * 256;      // 0..1023
            int m  = idx >> 4;            // 0..63
            int kk = idx & 15;            // 0..15
            As[kk][m] = X[(size_t)(row0 + m) * DMODEL + k0 + kk];
            Bs[kk][m] = W[(size_t)(col0 + m) * DMODEL + k0 + kk];
        }
        __syncthreads();
        #pragma unroll
        for (int kk = 0; kk < 16; kk++) {
            float a[4], b[4];
            #pragma unroll
            for (int i = 0; i < 4; i++) a[i] = As[kk][ty * 4 + i];
            #pragma unroll
            for (int j = 0; j < 4; j++) b[j] = Bs[kk][tx * 4 + j];
            #pragma unroll
            for (int i = 0; i < 4; i++)
                #pragma unroll
                for (int j = 0; j < 4; j++)
                    acc[i][j] += a[i] * b[j];
        }
        __syncthreads();
    }

    #pragma unroll
    for (int i = 0; i < 4; i++) {
        int r = row0 + ty * 4 + i;
        #pragma unroll
        for (int j = 0; j < 4; j++) {
            int c = col0 + tx * 4 + j;
            float v = acc[i][j];
            if (bias) v += bias[c];
            v *= scale;
            if (relu) v = fmaxf(v, 0.f);
            if (headmajor) {
                // z = h*BATCH + b ; Y[z, n, dh]
                int h = c >> 6, dh = c & 63;
                int b = r >> 10, n = r & 1023;
                Y[(size_t)((h << 2) | b) * (NSEQ * DHEAD) + (size_t)n * DHEAD + dh] = v;
            } else {
                Y[(size_t)r * DMODEL + c] = v;
            }
        }
    }
}

// sign(sum |T[row,:]|) per row of 64 -> 0.0 or 1.0
__launch_bounds__(256)
__global__ void rowmask_kernel(const float* __restrict__ T, float* __restrict__ out)
{
    int r = blockIdx.x * blockDim.x + threadIdx.x;   // 65536 rows
    float s = 0.f;
    #pragma unroll
    for (int i = 0; i < DHEAD; i++) s += fabsf(T[(size_t)r * DHEAD + i]);
    out[r] = (s == 0.f) ? 0.f : 1.f;
}

// ---------------------------------------------------------------------------
// Pass 1: per (n,m), online max & sum of exp over z=0..63
// Q already scaled by 1/sqrt(DH). grid: (m-tile, n-tile) of 32x32
// ---------------------------------------------------------------------------
__launch_bounds__(256)
__global__ void attn_pass1(const float* __restrict__ Q, const float* __restrict__ K,
                           const float* __restrict__ km,
                           float* __restrict__ Mout, float* __restrict__ Sout)
{
    __shared__ float Qs[32][65];
    __shared__ float Ks[32][65];
    __shared__ float kms[32];
    const int bx = blockIdx.x;   // m tile
    const int by = blockIdx.y;   // n tile
    const int tid = threadIdx.x;
    const int mloc = tid & 31;
    const int nbase = tid >> 5;  // 0..7

    float mrun[4], srun[4];
    #pragma unroll
    for (int i = 0; i < 4; i++) { mrun[i] = -INFINITY; srun[i] = 0.f; }

    for (int z = 0; z < ZTOT; z++) {
        #pragma unroll
        for (int i = 0; i < 8; i++) {
            int idx = tid + i * 256;   // 0..2047
            int r = idx >> 6, d = idx & 63;
            Qs[r][d] = Q[(size_t)(z * NSEQ + by * 32 + r) * DHEAD + d];
            Ks[r][d] = K[(size_t)(z * NSEQ + bx * 32 + r) * DHEAD + d];
        }
        if (tid < 32) kms[tid] = km[z * NSEQ + bx * 32 + tid];
        __syncthreads();
        #pragma unroll
        for (int i = 0; i < 4; i++) {
            int nl = nbase + 8 * i;
            float s = 0.f;
            #pragma unroll
            for (int d = 0; d < DHEAD; d++) s += Qs[nl][d] * Ks[mloc][d];
            if (kms[mloc] == 0.f) s = NEG_BIG;
            float mo = mrun[i];
            float mn = fmaxf(mo, s);
            srun[i] = srun[i] * expf(mo - mn) + expf(s - mn);
            mrun[i] = mn;
        }
        __syncthreads();
    }
    #pragma unroll
    for (int i = 0; i < 4; i++) {
        int n = by * 32 + nbase + 8 * i;
        int m = bx * 32 + mloc;
        Mout[(size_t)n * NSEQ + m] = mrun[i];
        Sout[(size_t)n * NSEQ + m] = srun[i];
    }
}

// ---------------------------------------------------------------------------
// Pass 2: per z, n-tile: out[z, n, :] = sum_m (exp(s-M)/S) * V[z, m, :]
// then epilogue applies query_mask, from_heads layout, key_padding valid.
// grid: x = n-tile (32), y = z (64)
// ---------------------------------------------------------------------------
__launch_bounds__(256)
__global__ void attn_pass2(const float* __restrict__ Q, const float* __restrict__ K,
                           const float* __restrict__ V, const float* __restrict__ km,
                           const float* __restrict__ qm, const float* __restrict__ Msm,
                           const float* __restrict__ Ssm,
                           const unsigned char* __restrict__ pad,
                           float* __restrict__ attn_out)
{
    __shared__ float Qs[32][65];
    __shared__ float Ks[32][65];
    __shared__ float Vs[32][65];
    __shared__ float Ps[32][33];
    __shared__ float kms[32];
    const int z = blockIdx.y;
    const int n0 = blockIdx.x * 32;
    const int tid = threadIdx.x;

    #pragma unroll
    for (int i = 0; i < 8; i++) {
        int idx = tid + i * 256;
        int r = idx >> 6, d = idx & 63;
        Qs[r][d] = Q[(size_t)(z * NSEQ + n0 + r) * DHEAD + d];
    }
    const int nl = tid >> 3;         // 0..31
    const int d0 = (tid & 7) * 8;    // 0,8,...,56
    float acc[8] = {};
    __syncthreads();

    for (int mt = 0; mt < 32; mt++) {
        int m0 = mt * 32;
        #pragma unroll
        for (int i = 0; i < 8; i++) {
            int idx = tid + i * 256;
            int r = idx >> 6, d = idx & 63;
            Ks[r][d] = K[(size_t)(z * NSEQ + m0 + r) * DHEAD + d];
            Vs[r][d] = V[(size_t)(z * NSEQ + m0 + r) * DHEAD + d];
        }
        if (tid < 32) kms[tid] = km[z * NSEQ + m0 + tid];
        __syncthreads();
        // score+softmax tile: thread -> 4 (n,m) pairs
        {
            int mloc = tid & 31;
            int nbase = tid >> 5;
            #pragma unroll
            for (int i = 0; i < 4; i++) {
                int nn = nbase + 8 * i;
                float s = 0.f;
                #pragma unroll
                for (int d = 0; d < DHEAD; d++) s += Qs[nn][d] * Ks[mloc][d];
                if (kms[mloc] == 0.f) s = NEG_BIG;
                size_t g = (size_t)(n0 + nn) * NSEQ + (m0 + mloc);
                Ps[nn][mloc] = expf(s - Msm[g]) / Ssm[g];
            }
        }
        __syncthreads();
        #pragma unroll 8
        for (int mm = 0; mm < 32; mm++) {
            float p = Ps[nl][mm];
            #pragma unroll
            for (int j = 0; j < 8; j++) acc[j] += p * Vs[mm][d0 + j];
        }
        __syncthreads();
    }

    // epilogue: attn *= query_mask ; from_heads ; * (~key_padding)
    float qmv = qm[z * NSEQ + n0 + nl];
    int h = z >> 2, b = z & 3;
    int n = n0 + nl;
    float valid = pad[b * NSEQ + n] ? 0.f : 1.f;
    float f = qmv * valid;
    #pragma unroll
    for (int j = 0; j < 8; j++)
        attn_out[(size_t)(b * NSEQ + n) * DMODEL + h * DHEAD + d0 + j] = acc[j] * f;
}

// ---------------------------------------------------------------------------
// LayerNorm over last dim (1024). mode 0: v = A + B, out = LN(v)*g+beta
// mode 1: v = A*valid + B, out = (LN(v)*g+beta)*valid
// one block per row (4096 rows)
// ---------------------------------------------------------------------------
__launch_bounds__(256)
__global__ void ln_kernel(const float* __restrict__ A, const float* __restrict__ Bv,
                          const float* __restrict__ g, const float* __restrict__ beta,
                          const unsigned char* __restrict__ pad,
                          int mode, float* __restrict__ out)
{
    const int row = blockIdx.x;
    const int tid = threadIdx.x;
    const float valid = pad[row] ? 0.f : 1.f;
    __shared__ float red[4];

    float v[4];
    float sum = 0.f;
    #pragma unroll
    for (int i = 0; i < 4; i++) {
        int c = tid + i * 256;
        float a = A[(size_t)row * DMODEL + c];
        float b = Bv[(size_t)row * DMODEL + c];
        float t = (mode == 0) ? (a + b) : (a * valid + b);
        v[i] = t;
        sum += t;
    }
    #pragma unroll
    for (int off = 32; off > 0; off >>= 1) sum += __shfl_down(sum, off, 64);
    int wave = tid >> 6, lane = tid & 63;
    if (lane == 0) red[wave] = sum;
    __syncthreads();
    float mean = (red[0] + red[1] + red[2] + red[3]) * (1.f / DMODEL);

    float sq = 0.f;
    #pragma unroll
    for (int i = 0; i < 4; i++) { float d = v[i] - mean; sq += d * d; }
    __syncthreads();
    #pragma unroll
    for (int off = 32; off > 0; off >>= 1) sq += __shfl_down(sq, off, 64);
    if (lane == 0) red[wave] = sq;
    __syncthreads();
    float var = (red[0] + red[1] + red[2] + red[3]) * (1.f / DMODEL);
    float rstd = rsqrtf(var + 1e-5f);
    float oscale = (mode == 0) ? 1.f : valid;

    #pragma unroll
    for (int i = 0; i < 4; i++) {
        int c = tid + i * 256;
        out[(size_t)row * DMODEL + c] = ((v[i] - mean) * rstd * g[c] + beta[c]) * oscale;
    }
}

// ---------------------------------------------------------------------------
extern "C" void kernel_launch(void* const* d_in, const int* in_sizes, int n_in,
                              void* d_out, int out_size, void* d_ws, size_t ws_size,
                              hipStream_t stream)
{
    const float* x   = (const float*)d_in[0];
    const unsigned char* pad = (const unsigned char*)d_in[1]; // all-False bools (bytes or i32: zeros either way)
    const float* Wq  = (const float*)d_in[2];
    const float* Wk  = (const float*)d_in[3];
    const float* Wv  = (const float*)d_in[4];
    const float* W1  = (const float*)d_in[5];
    const float* b1  = (const float*)d_in[6];
    const float* W2  = (const float*)d_in[7];
    const float* b2  = (const float*)d_in[8];
    const float* g1  = (const float*)d_in[9];
    const float* be1 = (const float*)d_in[10];
    const float* g2  = (const float*)d_in[11];
    const float* be2 = (const float*)d_in[12];
    float* out = (float*)d_out;

    // workspace layout (floats); total ~109.6 MB
    float* ws  = (float*)d_ws;
    float* Q    = ws;                    // 4,194,304
    float* Kh   = Q    + 4194304;        // 4,194,304
    float* Vh   = Kh   + 4194304;        // 4,194,304
    float* km   = Vh   + 4194304;        // 65,536
    float* qm   = km   + 65536;          // 65,536
    float* Msm  = qm   + 65536;          // 1,048,576
    float* Ssm  = Msm  + 1048576;        // 1,048,576
    float* attn = Ssm  + 1048576;        // 4,194,304
    float* h    = attn + 4194304;        // 4,194,304
    float* ff1  = h    + 4194304;        // 4,194,304

    dim3 gg(16, 64);
    // projections (Q gets the 1/sqrt(64) score scale folded in), head-major out
    gemm_xwt<<<gg, 256, 0, stream>>>(x, Wq, nullptr, Q,  0.125f, 0, 1);
    gemm_xwt<<<gg, 256, 0, stream>>>(x, Wk, nullptr, Kh, 1.0f,   0, 1);
    gemm_xwt<<<gg, 256, 0, stream>>>(x, Wv, nullptr, Vh, 1.0f,   0, 1);
    // sign masks
    rowmask_kernel<<<256, 256, 0, stream>>>(Kh, km);
    rowmask_kernel<<<256, 256, 0, stream>>>(Q,  qm);
    // softmax over z: stats then apply+PV
    attn_pass1<<<dim3(32, 32), 256, 0, stream>>>(Q, Kh, km, Msm, Ssm);
    attn_pass2<<<dim3(32, 64), 256, 0, stream>>>(Q, Kh, Vh, km, qm, Msm, Ssm, pad, attn);
    // h = LN(x + attn_out)
    ln_kernel<<<NROWS, 256, 0, stream>>>(x, attn, g1, be1, pad, 0, h);
    // FFN
    gemm_xwt<<<gg, 256, 0, stream>>>(h,   W1, b1, ff1, 1.0f, 1, 0);
    gemm_xwt<<<gg, 256, 0, stream>>>(ff1, W2, b2, out, 1.0f, 0, 0);  // ff2 staged in d_out
    // out = LN(ff*valid + h) * valid   (in-place over d_out)
    ln_kernel<<<NROWS, 256, 0, stream>>>(out, h, g2, be2, pad, 1, out);
}

// Round 2
// 284.958 us; speedup vs baseline: 8.2659x; 8.2659x over previous
//
#include <hip/hip_runtime.h>
#include <math.h>

typedef unsigned short u16;
typedef unsigned char  u8;
typedef unsigned int   u32;
typedef __attribute__((ext_vector_type(8))) short bf16x8;
typedef __attribute__((ext_vector_type(4))) float f32x4;

#define NSEQ   1024
#define DMODEL 1024
#define ZTOT   64

typedef const __attribute__((address_space(1))) void* gp1;
typedef __attribute__((address_space(3))) void* lp3;

__device__ __forceinline__ void gload16(const void* g, void* l) {
    __builtin_amdgcn_global_load_lds((gp1)g, (lp3)l, 16, 0, 0);
}

__device__ __forceinline__ u16 f2bf(float f) {
    u32 u = __builtin_bit_cast(u32, f);
    return (u16)((u + 0x7FFFu + ((u >> 16) & 1u)) >> 16);
}

// ---------------------------------------------------------------------------
// fp32 -> bf16 elementwise (grid sized exactly, n % 1024 == 0)
// ---------------------------------------------------------------------------
__launch_bounds__(256)
__global__ void cvt_bf16(const float* __restrict__ in, u16* __restrict__ out) {
    int i = (blockIdx.x * 256 + threadIdx.x) * 4;
    float4 v = *(const float4*)(in + i);
    uint2 o;
    o.x = (u32)f2bf(v.x) | ((u32)f2bf(v.y) << 16);
    o.y = (u32)f2bf(v.z) | ((u32)f2bf(v.w) << 16);
    *(uint2*)(out + i) = o;
}

// sign(sum |row|) over 64 bf16 -> 0/1  (zero iff every |elem| == 0)
__launch_bounds__(256)
__global__ void rowmask_bf(const u16* __restrict__ T, float* __restrict__ out) {
    int r = blockIdx.x * 256 + threadIdx.x;
    const uint4* p = (const uint4*)(T + (size_t)r * 64);
    u32 acc = 0;
    #pragma unroll
    for (int i = 0; i < 8; i++) {
        uint4 q = p[i];
        acc |= (q.x | q.y | q.z | q.w) & 0x7fff7fffu;
    }
    out[r] = acc ? 1.f : 0.f;
}

// ---------------------------------------------------------------------------
// bf16 MFMA GEMM, D[r,c] = sum_k A[r,k]*B[c,k]   (K = 1024)
// BM=128, BN=64, BK=32; 4 waves, each 64x32 (4x2 frags of 16x16)
// MODE 0: head-major bf16 out (proj Q/K), *scale
// MODE 1: Vt out [z][dh][n] bf16  (call with A=W, B=x: D[channel][token])
// MODE 2: +bias, relu, bf16 out row-major
// MODE 3: +bias, f32 out row-major
// ---------------------------------------------------------------------------
template <int MODE>
__launch_bounds__(256)
__global__ void gemm_bt(const u16* __restrict__ A, const u16* __restrict__ B,
                        const float* __restrict__ bias, void* __restrict__ outp,
                        float scale)
{
    __shared__ __align__(16) u16 lA[128 * 32];
    __shared__ __align__(16) u16 lB[64 * 32];
    const int tid = threadIdx.x, lane = tid & 63, w = tid >> 6;
    const int frow = lane & 15, koct = lane >> 4;
    const int col0 = blockIdx.x * 64, row0 = blockIdx.y * 128;
    const int wrow = (w >> 1) * 64, wcol = (w & 1) * 32;
    f32x4 acc[4][2] = {};

    for (int k0 = 0; k0 < 1024; k0 += 32) {
        // stage A(8KB): 2 chunks/thread, B(4KB): 1 chunk/thread; slot-swizzled source
        {
            int p = tid;
            int row = p >> 2, sl = p & 3, ssl = sl ^ ((row >> 1) & 3);
            gload16(A + (size_t)(row0 + row) * 1024 + k0 + ssl * 8, (char*)lA + p * 16);
            p = tid + 256; row = p >> 2; sl = p & 3; ssl = sl ^ ((row >> 1) & 3);
            gload16(A + (size_t)(row0 + row) * 1024 + k0 + ssl * 8, (char*)lA + p * 16);
            p = tid; row = p >> 2; sl = p & 3; ssl = sl ^ ((row >> 1) & 3);
            gload16(B + (size_t)(col0 + row) * 1024 + k0 + ssl * 8, (char*)lB + p * 16);
        }
        __syncthreads();
        bf16x8 af[4], bf2[2];
        #pragma unroll
        for (int i = 0; i < 4; i++) {
            int r = wrow + i * 16 + frow;
            int sl = koct ^ ((r >> 1) & 3);
            af[i] = *(const bf16x8*)((const char*)lA + r * 64 + sl * 16);
        }
        #pragma unroll
        for (int j = 0; j < 2; j++) {
            int r = wcol + j * 16 + frow;
            int sl = koct ^ ((r >> 1) & 3);
            bf2[j] = *(const bf16x8*)((const char*)lB + r * 64 + sl * 16);
        }
        #pragma unroll
        for (int i = 0; i < 4; i++)
            #pragma unroll
            for (int j = 0; j < 2; j++)
                acc[i][j] = __builtin_amdgcn_mfma_f32_16x16x32_bf16(af[i], bf2[j], acc[i][j], 0, 0, 0);
        __syncthreads();
    }

    #pragma unroll
    for (int i = 0; i < 4; i++) {
        #pragma unroll
        for (int j = 0; j < 2; j++) {
            #pragma unroll
            for (int q = 0; q < 4; q++) {
                int r = row0 + wrow + i * 16 + koct * 4 + q;
                int c = col0 + wcol + j * 16 + frow;
                float v = acc[i][j][q];
                if constexpr (MODE == 0) {
                    v *= scale;  // fold 1/sqrt(DH) into Q
                    // z = (c>>6)*4 + (r>>10); Qh[z][n][dh]
                    ((u16*)outp)[(size_t)((c >> 6) * 4 + (r >> 10)) * 65536 +
                                 (size_t)(r & 1023) * 64 + (c & 63)] = f2bf(v);
                } else if constexpr (MODE == 1) {
                    // r = channel, c = token; Vt[z][dh][s]
                    ((u16*)outp)[(size_t)((r >> 6) * 4 + (c >> 10)) * 65536 +
                                 (size_t)(r & 63) * 1024 + (c & 1023)] = f2bf(v);
                } else if constexpr (MODE == 2) {
                    v += bias[c];
                    v = fmaxf(v, 0.f);
                    ((u16*)outp)[(size_t)r * 1024 + c] = f2bf(v);
                } else {
                    v += bias[c];
                    ((float*)outp)[(size_t)r * 1024 + c] = v;
                }
            }
        }
    }
}

// ---------------------------------------------------------------------------
// Pass 1: partial[zg][n][m] = sum_{z in zg*16..+16} exp(s_znm) * km01(z,m)
// block = 64n x 64m, 4 waves (2x2 quadrants of 32x32), MFMA scores
// ---------------------------------------------------------------------------
__launch_bounds__(256)
__global__ void attn_pass1(const u16* __restrict__ Qh, const u16* __restrict__ Kh,
                           const float* __restrict__ km, float* __restrict__ partial)
{
    __shared__ __align__(16) u16 lQ[64 * 64];
    __shared__ __align__(16) u16 lK[64 * 64];
    const int tid = threadIdx.x, lane = tid & 63, w = tid >> 6;
    const int frow = lane & 15, koct = lane >> 4;
    const int m0 = blockIdx.x * 64, n0 = blockIdx.y * 64, zg = blockIdx.z;
    const int wn = (w >> 1) * 32, wm = (w & 1) * 32;
    f32x4 ssum[2][2] = {};

    for (int z = zg * 16; z < zg * 16 + 16; z++) {
        #pragma unroll
        for (int i = 0; i < 2; i++) {
            int p = tid + i * 256;
            int row = p >> 3, sl = p & 7, ssl = sl ^ (row & 7);
            gload16(Qh + (size_t)(z * NSEQ + n0 + row) * 64 + ssl * 8, (char*)lQ + p * 16);
            gload16(Kh + (size_t)(z * NSEQ + m0 + row) * 64 + ssl * 8, (char*)lK + p * 16);
        }
        __syncthreads();
        f32x4 s[2][2] = {};
        #pragma unroll
        for (int ks = 0; ks < 2; ks++) {
            bf16x8 a[2], b2[2];
            #pragma unroll
            for (int i = 0; i < 2; i++) {
                int r = wn + i * 16 + frow;
                int sl = (ks * 4 + koct) ^ (r & 7);
                a[i] = *(const bf16x8*)((const char*)lQ + r * 128 + sl * 16);
            }
            #pragma unroll
            for (int j = 0; j < 2; j++) {
                int r = wm + j * 16 + frow;
                int sl = (ks * 4 + koct) ^ (r & 7);
                b2[j] = *(const bf16x8*)((const char*)lK + r * 128 + sl * 16);
            }
            #pragma unroll
            for (int i = 0; i < 2; i++)
                #pragma unroll
                for (int j = 0; j < 2; j++)
                    s[i][j] = __builtin_amdgcn_mfma_f32_16x16x32_bf16(a[i], b2[j], s[i][j], 0, 0, 0);
        }
        #pragma unroll
        for (int j = 0; j < 2; j++) {
            float km01 = km[z * NSEQ + m0 + wm + j * 16 + frow];
            #pragma unroll
            for (int i = 0; i < 2; i++)
                #pragma unroll
                for (int q = 0; q < 4; q++)
                    ssum[i][j][q] += __expf(s[i][j][q]) * km01;
        }
        __syncthreads();
    }
    #pragma unroll
    for (int i = 0; i < 2; i++) {
        #pragma unroll
        for (int j = 0; j < 2; j++) {
            #pragma unroll
            for (int q = 0; q < 4; q++) {
                int ng = n0 + wn + i * 16 + koct * 4 + q;
                int mg = m0 + wm + j * 16 + frow;
                partial[(size_t)zg * 1048576 + (size_t)ng * NSEQ + mg] = ssum[i][j][q];
            }
        }
    }
}

// invS = 1 / (p0+p1+p2+p3)
__launch_bounds__(256)
__global__ void sum_inv(const float* __restrict__ p, float* __restrict__ invS) {
    int i = (blockIdx.x * 256 + threadIdx.x) * 4;
    float4 a = *(const float4*)(p + i);
    float4 b = *(const float4*)(p + 1048576 + i);
    float4 c = *(const float4*)(p + 2097152 + i);
    float4 d = *(const float4*)(p + 3145728 + i);
    float4 r;
    float s;
    s = a.x + b.x + c.x + d.x; r.x = s > 0.f ? 1.f / s : 0.f;
    s = a.y + b.y + c.y + d.y; r.y = s > 0.f ? 1.f / s : 0.f;
    s = a.z + b.z + c.z + d.z; r.z = s > 0.f ? 1.f / s : 0.f;
    s = a.w + b.w + c.w + d.w; r.w = s > 0.f ? 1.f / s : 0.f;
    *(float4*)(invS + i) = r;
}

// ---------------------------------------------------------------------------
// Pass 2: per z, out[z,n,:] = sum_m (exp(s)*km*invS) V[m,:]; epilogue applies
// query mask + padding + from_heads. block = 128n x z, 4 waves (32n each).
// ---------------------------------------------------------------------------
__launch_bounds__(256)
__global__ void attn_pass2(const u16* __restrict__ Qh, const u16* __restrict__ Kh,
                           const u16* __restrict__ Vt, const float* __restrict__ km,
                           const float* __restrict__ qm, const float* __restrict__ invS,
                           const u8* __restrict__ pad, float* __restrict__ attn)
{
    __shared__ __align__(16) u16 lQ[128 * 64];
    __shared__ __align__(16) u16 lK[64 * 64];
    __shared__ __align__(16) u16 lV[64 * 64];   // Vt tile: [d][m]
    __shared__ __align__(16) u16 lP[128 * 64];
    const int tid = threadIdx.x, lane = tid & 63, w = tid >> 6;
    const int frow = lane & 15, koct = lane >> 4;
    const int z = blockIdx.y, n0 = blockIdx.x * 128;
    const int hh = z >> 2, bb = z & 3;
    const int wrow = w * 32;

    #pragma unroll
    for (int i = 0; i < 4; i++) {
        int p = tid + i * 256;
        int row = p >> 3, sl = p & 7, ssl = sl ^ (row & 7);
        gload16(Qh + (size_t)(z * NSEQ + n0 + row) * 64 + ssl * 8, (char*)lQ + p * 16);
    }

    f32x4 oacc[2][4] = {};

    for (int mt = 0; mt < 16; mt++) {
        const int m0 = mt * 64;
        #pragma unroll
        for (int i = 0; i < 2; i++) {
            int p = tid + i * 256;
            int row = p >> 3, sl = p & 7, ssl = sl ^ (row & 7);
            gload16(Kh + (size_t)(z * NSEQ + m0 + row) * 64 + ssl * 8, (char*)lK + p * 16);
            gload16(Vt + (size_t)z * 65536 + (size_t)row * 1024 + m0 + ssl * 8, (char*)lV + p * 16);
        }
        __syncthreads();
        // scores: rows wrow..+31 x all 64 m
        f32x4 s[2][4] = {};
        #pragma unroll
        for (int ks = 0; ks < 2; ks++) {
            bf16x8 a[2], kb[4];
            #pragma unroll
            for (int i = 0; i < 2; i++) {
                int r = wrow + i * 16 + frow;
                int sl = (ks * 4 + koct) ^ (r & 7);
                a[i] = *(const bf16x8*)((const char*)lQ + r * 128 + sl * 16);
            }
            #pragma unroll
            for (int j = 0; j < 4; j++) {
                int r = j * 16 + frow;
                int sl = (ks * 4 + koct) ^ (r & 7);
                kb[j] = *(const bf16x8*)((const char*)lK + r * 128 + sl * 16);
            }
            #pragma unroll
            for (int i = 0; i < 2; i++)
                #pragma unroll
                for (int j = 0; j < 4; j++)
                    s[i][j] = __builtin_amdgcn_mfma_f32_16x16x32_bf16(a[i], kb[j], s[i][j], 0, 0, 0);
        }
        // P = exp(s)*km*invS -> bf16 -> lP (swizzled)
        #pragma unroll
        for (int j = 0; j < 4; j++) {
            int mg = m0 + j * 16 + frow;
            float km01 = km[z * NSEQ + mg];
            int mloc = j * 16 + frow;
            #pragma unroll
            for (int i = 0; i < 2; i++) {
                #pragma unroll
                for (int q = 0; q < 4; q++) {
                    int nl = wrow + i * 16 + koct * 4 + q;
                    float pv = __expf(s[i][j][q]) * km01 * invS[(size_t)(n0 + nl) * NSEQ + mg];
                    int sl = (mloc >> 3) ^ (nl & 7);
                    *(u16*)((char*)lP + nl * 128 + sl * 16 + (mloc & 7) * 2) = f2bf(pv);
                }
            }
        }
        __syncthreads();
        // PV: A = P rows (own 32-row stripe), B = Vt rows (d-major)
        #pragma unroll
        for (int ks = 0; ks < 2; ks++) {
            bf16x8 pa[2], vb[4];
            #pragma unroll
            for (int i = 0; i < 2; i++) {
                int r = wrow + i * 16 + frow;
                int sl = (ks * 4 + koct) ^ (r & 7);
                pa[i] = *(const bf16x8*)((const char*)lP + r * 128 + sl * 16);
            }
            #pragma unroll
            for (int dj = 0; dj < 4; dj++) {
                int r = dj * 16 + frow;
                int sl = (ks * 4 + koct) ^ (r & 7);
                vb[dj] = *(const bf16x8*)((const char*)lV + r * 128 + sl * 16);
            }
            #pragma unroll
            for (int i = 0; i < 2; i++)
                #pragma unroll
                for (int dj = 0; dj < 4; dj++)
                    oacc[i][dj] = __builtin_amdgcn_mfma_f32_16x16x32_bf16(pa[i], vb[dj], oacc[i][dj], 0, 0, 0);
        }
        __syncthreads();
    }

    #pragma unroll
    for (int i = 0; i < 2; i++) {
        #pragma unroll
        for (int q = 0; q < 4; q++) {
            int ns = n0 + wrow + i * 16 + koct * 4 + q;
            float f = qm[z * NSEQ + ns] * (pad[bb * NSEQ + ns] ? 0.f : 1.f);
            #pragma unroll
            for (int dj = 0; dj < 4; dj++) {
                int d = dj * 16 + frow;
                attn[(size_t)(bb * NSEQ + ns) * DMODEL + hh * 64 + d] = oacc[i][dj][q] * f;
            }
        }
    }
}

// ---------------------------------------------------------------------------
// LayerNorm over last dim (1024), one block per row.
// mode 0: v = A + B  -> out f32 (+ bf16 copy)
// mode 1: v = A*valid + B -> out f32 * valid
// ---------------------------------------------------------------------------
__launch_bounds__(256)
__global__ void ln_kernel(const float* __restrict__ A, const float* __restrict__ Bv,
                          const float* __restrict__ g, const float* __restrict__ beta,
                          const u8* __restrict__ pad, int mode,
                          float* __restrict__ out, u16* __restrict__ outb)
{
    const int row = blockIdx.x, tid = threadIdx.x;
    const int lane = tid & 63, wv = tid >> 6;
    const float valid = pad[row] ? 0.f : 1.f;
    __shared__ float red[4];

    float4 va = *(const float4*)(A + (size_t)row * 1024 + tid * 4);
    float4 vb = *(const float4*)(Bv + (size_t)row * 1024 + tid * 4);
    float v[4];
    if (mode == 0) {
        v[0] = va.x + vb.x; v[1] = va.y + vb.y; v[2] = va.z + vb.z; v[3] = va.w + vb.w;
    } else {
        v[0] = va.x * valid + vb.x; v[1] = va.y * valid + vb.y;
        v[2] = va.z * valid + vb.z; v[3] = va.w * valid + vb.w;
    }
    float s = v[0] + v[1] + v[2] + v[3];
    #pragma unroll
    for (int off = 32; off > 0; off >>= 1) s += __shfl_down(s, off, 64);
    if (lane == 0) red[wv] = s;
    __syncthreads();
    float mean = (red[0] + red[1] + red[2] + red[3]) * (1.f / 1024.f);
    float sq = 0.f;
    #pragma unroll
    for (int k = 0; k < 4; k++) { float d = v[k] - mean; sq += d * d; }
    __syncthreads();
    #pragma unroll
    for (int off = 32; off > 0; off >>= 1) sq += __shfl_down(sq, off, 64);
    if (lane == 0) red[wv] = sq;
    __syncthreads();
    float var = (red[0] + red[1] + red[2] + red[3]) * (1.f / 1024.f);
    float rstd = rsqrtf(var + 1e-5f);
    float osc = (mode == 0) ? 1.f : valid;
    #pragma unroll
    for (int k = 0; k < 4; k++) {
        int c = tid * 4 + k;
        float o = ((v[k] - mean) * rstd * g[c] + beta[c]) * osc;
        out[(size_t)row * 1024 + c] = o;
        if (outb) outb[(size_t)row * 1024 + c] = f2bf(o);
    }
}

// ---------------------------------------------------------------------------
extern "C" void kernel_launch(void* const* d_in, const int* in_sizes, int n_in,
                              void* d_out, int out_size, void* d_ws, size_t ws_size,
                              hipStream_t stream)
{
    const float* x   = (const float*)d_in[0];
    const u8*    pad = (const u8*)d_in[1];
    const float* Wq  = (const float*)d_in[2];
    const float* Wk  = (const float*)d_in[3];
    const float* Wv  = (const float*)d_in[4];
    const float* W1  = (const float*)d_in[5];
    const float* b1  = (const float*)d_in[6];
    const float* W2  = (const float*)d_in[7];
    const float* b2  = (const float*)d_in[8];
    const float* g1  = (const float*)d_in[9];
    const float* be1 = (const float*)d_in[10];
    const float* g2  = (const float*)d_in[11];
    const float* be2 = (const float*)d_in[12];
    float* out = (float*)d_out;

    // workspace (~99 MB)
    u16* xb   = (u16*)d_ws;            // 4M
    u16* Wqb  = xb   + 4194304;        // 1M each
    u16* Wkb  = Wqb  + 1048576;
    u16* Wvb  = Wkb  + 1048576;
    u16* W1b  = Wvb  + 1048576;
    u16* W2b  = W1b  + 1048576;
    u16* Qh   = W2b  + 1048576;        // 4M  [z][n][dh]
    u16* Kh   = Qh   + 4194304;        // 4M  [z][n][dh]
    u16* Vt   = Kh   + 4194304;        // 4M  [z][dh][n]
    u16* hb   = Vt   + 4194304;        // 4M
    u16* ff1b = hb   + 4194304;        // 4M
    float* km      = (float*)(ff1b + 4194304);  // 64K
    float* qm      = km      + 65536;           // 64K
    float* partial = qm      + 65536;           // 4M
    float* invS    = partial + 4194304;         // 1M
    float* h       = invS    + 1048576;         // 4M

    // bf16 conversions
    cvt_bf16<<<4096, 256, 0, stream>>>(x,  xb);
    cvt_bf16<<<1024, 256, 0, stream>>>(Wq, Wqb);
    cvt_bf16<<<1024, 256, 0, stream>>>(Wk, Wkb);
    cvt_bf16<<<1024, 256, 0, stream>>>(Wv, Wvb);
    cvt_bf16<<<1024, 256, 0, stream>>>(W1, W1b);
    cvt_bf16<<<1024, 256, 0, stream>>>(W2, W2b);

    // projections: Q (scaled 1/8), K head-major; V d-major via swapped operands
    gemm_bt<0><<<dim3(16, 32), 256, 0, stream>>>(xb, Wqb, nullptr, Qh, 0.125f);
    gemm_bt<0><<<dim3(16, 32), 256, 0, stream>>>(xb, Wkb, nullptr, Kh, 1.0f);
    gemm_bt<1><<<dim3(64, 8),  256, 0, stream>>>(Wvb, xb, nullptr, Vt, 1.0f);

    // sign masks
    rowmask_bf<<<256, 256, 0, stream>>>(Kh, km);
    rowmask_bf<<<256, 256, 0, stream>>>(Qh, qm);

    // softmax over z (two-phase: partial exp-sums, combine, apply + PV)
    attn_pass1<<<dim3(16, 16, 4), 256, 0, stream>>>(Qh, Kh, km, partial);
    sum_inv<<<1024, 256, 0, stream>>>(partial, invS);
    attn_pass2<<<dim3(8, 64), 256, 0, stream>>>(Qh, Kh, Vt, km, qm, invS, pad, out);

    // h = LN(x + attn)  (+ bf16 copy for FFN)
    ln_kernel<<<4096, 256, 0, stream>>>(x, out, g1, be1, pad, 0, h, hb);

    // FFN
    gemm_bt<2><<<dim3(16, 32), 256, 0, stream>>>(hb,   W1b, b1, ff1b, 1.0f);
    gemm_bt<3><<<dim3(16, 32), 256, 0, stream>>>(ff1b, W2b, b2, out,  1.0f);

    // out = LN(ff*valid + h) * valid   (in-place over d_out)
    ln_kernel<<<4096, 256, 0, stream>>>(out, h, g2, be2, pad, 1, out, nullptr);
}

// Round 3
// 236.145 us; speedup vs baseline: 9.9745x; 1.2067x over previous
//
#include <hip/hip_runtime.h>
#include <math.h>

typedef unsigned short u16;
typedef unsigned char  u8;
typedef unsigned int   u32;
typedef __attribute__((ext_vector_type(8))) short bf16x8;
typedef __attribute__((ext_vector_type(4))) float f32x4;

#define NSEQ   1024
#define DMODEL 1024
#define ZTOT   64

typedef const __attribute__((address_space(1))) void* gp1;
typedef __attribute__((address_space(3))) void* lp3;

__device__ __forceinline__ void gload16(const void* g, void* l) {
    __builtin_amdgcn_global_load_lds((gp1)g, (lp3)l, 16, 0, 0);
}

__device__ __forceinline__ u16 f2bf(float f) {
    u32 u = __builtin_bit_cast(u32, f);
    return (u16)((u + 0x7FFFu + ((u >> 16) & 1u)) >> 16);
}

// ---------------------------------------------------------------------------
// fp32 -> bf16 elementwise
// ---------------------------------------------------------------------------
__launch_bounds__(256)
__global__ void cvt_bf16(const float* __restrict__ in, u16* __restrict__ out) {
    int i = (blockIdx.x * 256 + threadIdx.x) * 4;
    float4 v = *(const float4*)(in + i);
    uint2 o;
    o.x = (u32)f2bf(v.x) | ((u32)f2bf(v.y) << 16);
    o.y = (u32)f2bf(v.z) | ((u32)f2bf(v.w) << 16);
    *(uint2*)(out + i) = o;
}

struct P5 { const float* in[5]; u16* out[5]; };
__launch_bounds__(256)
__global__ void cvt_bf16_5(P5 p) {
    int which = blockIdx.x >> 10;           // 5 matrices of 1M elems
    int blk   = blockIdx.x & 1023;
    int i = (blk * 256 + threadIdx.x) * 4;
    float4 v = *(const float4*)(p.in[which] + i);
    uint2 o;
    o.x = (u32)f2bf(v.x) | ((u32)f2bf(v.y) << 16);
    o.y = (u32)f2bf(v.z) | ((u32)f2bf(v.w) << 16);
    *(uint2*)(p.out[which] + i) = o;
}

// sign(sum |row|) over 64 bf16 -> 0/1
__launch_bounds__(256)
__global__ void rowmask_bf(const u16* __restrict__ T, float* __restrict__ out) {
    int r = blockIdx.x * 256 + threadIdx.x;
    const uint4* p = (const uint4*)(T + (size_t)r * 64);
    u32 acc = 0;
    #pragma unroll
    for (int i = 0; i < 8; i++) {
        uint4 q = p[i];
        acc |= (q.x | q.y | q.z | q.w) & 0x7fff7fffu;
    }
    out[r] = acc ? 1.f : 0.f;
}

// ---------------------------------------------------------------------------
// bf16 MFMA GEMM, D[r,c] = sum_k A[r,k]*B[c,k]   (K = 1024)
// BM=128, BN=64, BK=64; double-buffered staging; 4 waves 64x32 each
// MODE 0: head-major bf16 out (proj Q/K), *scale
// MODE 1: Vt out [z][dh][n] bf16  (A=W, B=x: D[channel][token])
// MODE 2: +bias, relu, bf16 out row-major
// MODE 3: +bias, f32 out row-major
// ---------------------------------------------------------------------------
template <int MODE>
__launch_bounds__(256)
__global__ void gemm_bt(const u16* __restrict__ A, const u16* __restrict__ B,
                        const float* __restrict__ bias, void* __restrict__ outp,
                        float scale)
{
    __shared__ __align__(16) u16 lA[2][128 * 64];
    __shared__ __align__(16) u16 lB[2][64 * 64];
    const int tid = threadIdx.x, lane = tid & 63, w = tid >> 6;
    const int frow = lane & 15, koct = lane >> 4;
    const int col0 = blockIdx.x * 64, row0 = blockIdx.y * 128;
    const int wrow = (w >> 1) * 64, wcol = (w & 1) * 32;
    f32x4 acc[4][2] = {};

    // stage k0 into buf: A 1024 chunks (4/thread), B 512 chunks (2/thread)
    auto stage = [&](int buf, int k0) {
        #pragma unroll
        for (int i = 0; i < 4; i++) {
            int p = tid + i * 256;
            int row = p >> 3, sl = p & 7, ssl = sl ^ (row & 7);
            gload16(A + (size_t)(row0 + row) * 1024 + k0 + ssl * 8, (char*)lA[buf] + p * 16);
        }
        #pragma unroll
        for (int i = 0; i < 2; i++) {
            int p = tid + i * 256;
            int row = p >> 3, sl = p & 7, ssl = sl ^ (row & 7);
            gload16(B + (size_t)(col0 + row) * 1024 + k0 + ssl * 8, (char*)lB[buf] + p * 16);
        }
    };

    stage(0, 0);
    __syncthreads();
    int buf = 0;
    for (int k0 = 0; k0 < 1024; k0 += 64) {
        if (k0 + 64 < 1024) stage(buf ^ 1, k0 + 64);
        #pragma unroll
        for (int ks = 0; ks < 2; ks++) {
            bf16x8 af[4], bf2[2];
            #pragma unroll
            for (int i = 0; i < 4; i++) {
                int r = wrow + i * 16 + frow;
                int sl = (ks * 4 + koct) ^ (r & 7);
                af[i] = *(const bf16x8*)((const char*)lA[buf] + r * 128 + sl * 16);
            }
            #pragma unroll
            for (int j = 0; j < 2; j++) {
                int r = wcol + j * 16 + frow;
                int sl = (ks * 4 + koct) ^ (r & 7);
                bf2[j] = *(const bf16x8*)((const char*)lB[buf] + r * 128 + sl * 16);
            }
            #pragma unroll
            for (int i = 0; i < 4; i++)
                #pragma unroll
                for (int j = 0; j < 2; j++)
                    acc[i][j] = __builtin_amdgcn_mfma_f32_16x16x32_bf16(af[i], bf2[j], acc[i][j], 0, 0, 0);
        }
        __syncthreads();
        buf ^= 1;
    }

    #pragma unroll
    for (int i = 0; i < 4; i++) {
        #pragma unroll
        for (int j = 0; j < 2; j++) {
            #pragma unroll
            for (int q = 0; q < 4; q++) {
                int r = row0 + wrow + i * 16 + koct * 4 + q;
                int c = col0 + wcol + j * 16 + frow;
                float v = acc[i][j][q];
                if constexpr (MODE == 0) {
                    v *= scale;
                    ((u16*)outp)[(size_t)((c >> 6) * 4 + (r >> 10)) * 65536 +
                                 (size_t)(r & 1023) * 64 + (c & 63)] = f2bf(v);
                } else if constexpr (MODE == 1) {
                    ((u16*)outp)[(size_t)((r >> 6) * 4 + (c >> 10)) * 65536 +
                                 (size_t)(r & 63) * 1024 + (c & 1023)] = f2bf(v);
                } else if constexpr (MODE == 2) {
                    v += bias[c];
                    v = fmaxf(v, 0.f);
                    ((u16*)outp)[(size_t)r * 1024 + c] = f2bf(v);
                } else {
                    v += bias[c];
                    ((float*)outp)[(size_t)r * 1024 + c] = v;
                }
            }
        }
    }
}

// ---------------------------------------------------------------------------
// Pass 1: partial[zg][n][m] = sum_{z in zg*16..+16} exp(s_znm) * km01(z,m)
// 64n x 64m block, 4 waves (2x2 quadrants of 32x32); double-buffered z staging
// ---------------------------------------------------------------------------
__launch_bounds__(256)
__global__ void attn_pass1(const u16* __restrict__ Qh, const u16* __restrict__ Kh,
                           const float* __restrict__ km, float* __restrict__ partial)
{
    __shared__ __align__(16) u16 lQ[2][64 * 64];
    __shared__ __align__(16) u16 lK[2][64 * 64];
    const int tid = threadIdx.x, lane = tid & 63, w = tid >> 6;
    const int frow = lane & 15, koct = lane >> 4;
    const int m0 = blockIdx.x * 64, n0 = blockIdx.y * 64, zg = blockIdx.z;
    const int wn = (w >> 1) * 32, wm = (w & 1) * 32;
    f32x4 ssum[2][2] = {};

    auto stage = [&](int buf, int z) {
        #pragma unroll
        for (int i = 0; i < 2; i++) {
            int p = tid + i * 256;
            int row = p >> 3, sl = p & 7, ssl = sl ^ (row & 7);
            gload16(Qh + (size_t)(z * NSEQ + n0 + row) * 64 + ssl * 8, (char*)lQ[buf] + p * 16);
            gload16(Kh + (size_t)(z * NSEQ + m0 + row) * 64 + ssl * 8, (char*)lK[buf] + p * 16);
        }
    };

    const int z0 = zg * 16;
    stage(0, z0);
    __syncthreads();
    int buf = 0;
    for (int zi = 0; zi < 16; zi++) {
        const int z = z0 + zi;
        if (zi < 15) stage(buf ^ 1, z + 1);
        f32x4 s[2][2] = {};
        #pragma unroll
        for (int ks = 0; ks < 2; ks++) {
            bf16x8 a[2], b2[2];
            #pragma unroll
            for (int i = 0; i < 2; i++) {
                int r = wn + i * 16 + frow;
                int sl = (ks * 4 + koct) ^ (r & 7);
                a[i] = *(const bf16x8*)((const char*)lQ[buf] + r * 128 + sl * 16);
            }
            #pragma unroll
            for (int j = 0; j < 2; j++) {
                int r = wm + j * 16 + frow;
                int sl = (ks * 4 + koct) ^ (r & 7);
                b2[j] = *(const bf16x8*)((const char*)lK[buf] + r * 128 + sl * 16);
            }
            #pragma unroll
            for (int i = 0; i < 2; i++)
                #pragma unroll
                for (int j = 0; j < 2; j++)
                    s[i][j] = __builtin_amdgcn_mfma_f32_16x16x32_bf16(a[i], b2[j], s[i][j], 0, 0, 0);
        }
        #pragma unroll
        for (int j = 0; j < 2; j++) {
            float km01 = km[z * NSEQ + m0 + wm + j * 16 + frow];
            #pragma unroll
            for (int i = 0; i < 2; i++)
                #pragma unroll
                for (int q = 0; q < 4; q++)
                    ssum[i][j][q] += __expf(s[i][j][q]) * km01;
        }
        __syncthreads();
        buf ^= 1;
    }
    #pragma unroll
    for (int i = 0; i < 2; i++)
        #pragma unroll
        for (int j = 0; j < 2; j++)
            #pragma unroll
            for (int q = 0; q < 4; q++) {
                int ng = n0 + wn + i * 16 + koct * 4 + q;
                int mg = m0 + wm + j * 16 + frow;
                partial[(size_t)zg * 1048576 + (size_t)ng * NSEQ + mg] = ssum[i][j][q];
            }
}

// invS = 1 / (p0+p1+p2+p3)
__launch_bounds__(256)
__global__ void sum_inv(const float* __restrict__ p, float* __restrict__ invS) {
    int i = (blockIdx.x * 256 + threadIdx.x) * 4;
    float4 a = *(const float4*)(p + i);
    float4 b = *(const float4*)(p + 1048576 + i);
    float4 c = *(const float4*)(p + 2097152 + i);
    float4 d = *(const float4*)(p + 3145728 + i);
    float4 r;
    float s;
    s = a.x + b.x + c.x + d.x; r.x = s > 0.f ? 1.f / s : 0.f;
    s = a.y + b.y + c.y + d.y; r.y = s > 0.f ? 1.f / s : 0.f;
    s = a.z + b.z + c.z + d.z; r.z = s > 0.f ? 1.f / s : 0.f;
    s = a.w + b.w + c.w + d.w; r.w = s > 0.f ? 1.f / s : 0.f;
    *(float4*)(invS + i) = r;
}

// ---------------------------------------------------------------------------
// Pass 2: per z, out[z,n,:] = sum_m (exp(s)*km*invS) V[m,:]
// 64 n-rows per block (wave w owns 16), Q frags hoisted to registers,
// double-buffered K/V staging, lP wave-private (no extra barrier).
// grid: x = n-tile (16), y = z (64)
// ---------------------------------------------------------------------------
__launch_bounds__(256)
__global__ void attn_pass2(const u16* __restrict__ Qh, const u16* __restrict__ Kh,
                           const u16* __restrict__ Vt, const float* __restrict__ km,
                           const float* __restrict__ qm, const float* __restrict__ invS,
                           const u8* __restrict__ pad, float* __restrict__ attn)
{
    __shared__ __align__(16) u16 lK[2][64 * 64];
    __shared__ __align__(16) u16 lV[2][64 * 64];   // Vt tile: [d][m]
    __shared__ __align__(16) u16 lP[64 * 64];
    const int tid = threadIdx.x, lane = tid & 63, w = tid >> 6;
    const int frow = lane & 15, koct = lane >> 4;
    const int z = blockIdx.y, n0 = blockIdx.x * 64;
    const int hh = z >> 2, bb = z & 3;
    const int wrow = w * 16;

    // Q fragments: loop-invariant, straight from global (L2-hot)
    bf16x8 aq[2];
    #pragma unroll
    for (int ks = 0; ks < 2; ks++)
        aq[ks] = *(const bf16x8*)(Qh + (size_t)(z * NSEQ + n0 + wrow + frow) * 64 + ks * 32 + koct * 8);

    auto stage = [&](int buf, int m0) {
        #pragma unroll
        for (int i = 0; i < 2; i++) {
            int p = tid + i * 256;
            int row = p >> 3, sl = p & 7, ssl = sl ^ (row & 7);
            gload16(Kh + (size_t)(z * NSEQ + m0 + row) * 64 + ssl * 8, (char*)lK[buf] + p * 16);
            gload16(Vt + (size_t)z * 65536 + (size_t)row * 1024 + m0 + ssl * 8, (char*)lV[buf] + p * 16);
        }
    };

    f32x4 oacc[4] = {};
    stage(0, 0);
    __syncthreads();
    int buf = 0;

    for (int mt = 0; mt < 16; mt++) {
        const int m0 = mt * 64;
        if (mt < 15) stage(buf ^ 1, m0 + 64);
        // scores: my 16 n-rows x 64 m
        f32x4 s[4] = {};
        #pragma unroll
        for (int ks = 0; ks < 2; ks++) {
            bf16x8 kb[4];
            #pragma unroll
            for (int j = 0; j < 4; j++) {
                int r = j * 16 + frow;
                int sl = (ks * 4 + koct) ^ (r & 7);
                kb[j] = *(const bf16x8*)((const char*)lK[buf] + r * 128 + sl * 16);
            }
            #pragma unroll
            for (int j = 0; j < 4; j++)
                s[j] = __builtin_amdgcn_mfma_f32_16x16x32_bf16(aq[ks], kb[j], s[j], 0, 0, 0);
        }
        // P = exp(s)*km*invS -> bf16 -> lP (wave-private 16-row stripe, swizzled)
        #pragma unroll
        for (int j = 0; j < 4; j++) {
            int mg = m0 + j * 16 + frow;
            int mloc = j * 16 + frow;
            float km01 = km[z * NSEQ + mg];
            #pragma unroll
            for (int q = 0; q < 4; q++) {
                int nl = wrow + koct * 4 + q;
                float pv = __expf(s[j][q]) * km01 * invS[(size_t)(n0 + nl) * NSEQ + mg];
                int sl = (mloc >> 3) ^ (nl & 7);
                *(u16*)((char*)lP + nl * 128 + sl * 16 + (mloc & 7) * 2) = f2bf(pv);
            }
        }
        // PV: A = my P stripe, B = Vt rows (d-major)
        #pragma unroll
        for (int ks = 0; ks < 2; ks++) {
            int r = wrow + frow;
            int sl = (ks * 4 + koct) ^ (r & 7);
            bf16x8 pa = *(const bf16x8*)((const char*)lP + r * 128 + sl * 16);
            bf16x8 vb[4];
            #pragma unroll
            for (int dj = 0; dj < 4; dj++) {
                int rr = dj * 16 + frow;
                int sv = (ks * 4 + koct) ^ (rr & 7);
                vb[dj] = *(const bf16x8*)((const char*)lV[buf] + rr * 128 + sv * 16);
            }
            #pragma unroll
            for (int dj = 0; dj < 4; dj++)
                oacc[dj] = __builtin_amdgcn_mfma_f32_16x16x32_bf16(pa, vb[dj], oacc[dj], 0, 0, 0);
        }
        __syncthreads();
        buf ^= 1;
    }

    #pragma unroll
    for (int q = 0; q < 4; q++) {
        int ns = n0 + wrow + koct * 4 + q;
        float f = qm[z * NSEQ + ns] * (pad[bb * NSEQ + ns] ? 0.f : 1.f);
        #pragma unroll
        for (int dj = 0; dj < 4; dj++) {
            int d = dj * 16 + frow;
            attn[(size_t)(bb * NSEQ + ns) * DMODEL + hh * 64 + d] = oacc[dj][q] * f;
        }
    }
}

// ---------------------------------------------------------------------------
// LayerNorm over last dim (1024), one block per row.
// mode 0: v = A + B  -> out f32 (+ bf16 copy)
// mode 1: v = A*valid + B -> out f32 * valid
// ---------------------------------------------------------------------------
__launch_bounds__(256)
__global__ void ln_kernel(const float* __restrict__ A, const float* __restrict__ Bv,
                          const float* __restrict__ g, const float* __restrict__ beta,
                          const u8* __restrict__ pad, int mode,
                          float* __restrict__ out, u16* __restrict__ outb)
{
    const int row = blockIdx.x, tid = threadIdx.x;
    const int lane = tid & 63, wv = tid >> 6;
    const float valid = pad[row] ? 0.f : 1.f;
    __shared__ float red[4];

    float4 va = *(const float4*)(A + (size_t)row * 1024 + tid * 4);
    float4 vb = *(const float4*)(Bv + (size_t)row * 1024 + tid * 4);
    float v[4];
    if (mode == 0) {
        v[0] = va.x + vb.x; v[1] = va.y + vb.y; v[2] = va.z + vb.z; v[3] = va.w + vb.w;
    } else {
        v[0] = va.x * valid + vb.x; v[1] = va.y * valid + vb.y;
        v[2] = va.z * valid + vb.z; v[3] = va.w * valid + vb.w;
    }
    float s = v[0] + v[1] + v[2] + v[3];
    #pragma unroll
    for (int off = 32; off > 0; off >>= 1) s += __shfl_down(s, off, 64);
    if (lane == 0) red[wv] = s;
    __syncthreads();
    float mean = (red[0] + red[1] + red[2] + red[3]) * (1.f / 1024.f);
    float sq = 0.f;
    #pragma unroll
    for (int k = 0; k < 4; k++) { float d = v[k] - mean; sq += d * d; }
    __syncthreads();
    #pragma unroll
    for (int off = 32; off > 0; off >>= 1) sq += __shfl_down(sq, off, 64);
    if (lane == 0) red[wv] = sq;
    __syncthreads();
    float var = (red[0] + red[1] + red[2] + red[3]) * (1.f / 1024.f);
    float rstd = rsqrtf(var + 1e-5f);
    float osc = (mode == 0) ? 1.f : valid;
    #pragma unroll
    for (int k = 0; k < 4; k++) {
        int c = tid * 4 + k;
        float o = ((v[k] - mean) * rstd * g[c] + beta[c]) * osc;
        out[(size_t)row * 1024 + c] = o;
        if (outb) outb[(size_t)row * 1024 + c] = f2bf(o);
    }
}

// ---------------------------------------------------------------------------
extern "C" void kernel_launch(void* const* d_in, const int* in_sizes, int n_in,
                              void* d_out, int out_size, void* d_ws, size_t ws_size,
                              hipStream_t stream)
{
    const float* x   = (const float*)d_in[0];
    const u8*    pad = (const u8*)d_in[1];
    const float* Wq  = (const float*)d_in[2];
    const float* Wk  = (const float*)d_in[3];
    const float* Wv  = (const float*)d_in[4];
    const float* W1  = (const float*)d_in[5];
    const float* b1  = (const float*)d_in[6];
    const float* W2  = (const float*)d_in[7];
    const float* b2  = (const float*)d_in[8];
    const float* g1  = (const float*)d_in[9];
    const float* be1 = (const float*)d_in[10];
    const float* g2  = (const float*)d_in[11];
    const float* be2 = (const float*)d_in[12];
    float* out = (float*)d_out;

    // workspace (~99 MB)
    u16* xb   = (u16*)d_ws;            // 4M elems
    u16* Wqb  = xb   + 4194304;
    u16* Wkb  = Wqb  + 1048576;
    u16* Wvb  = Wkb  + 1048576;
    u16* W1b  = Wvb  + 1048576;
    u16* W2b  = W1b  + 1048576;
    u16* Qh   = W2b  + 1048576;        // [z][n][dh]
    u16* Kh   = Qh   + 4194304;        // [z][n][dh]
    u16* Vt   = Kh   + 4194304;        // [z][dh][n]
    u16* hb   = Vt   + 4194304;
    u16* ff1b = hb   + 4194304;
    float* km      = (float*)(ff1b + 4194304);
    float* qm      = km      + 65536;
    float* partial = qm      + 65536;           // 4M f32 (4 z-group slabs)
    float* invS    = partial + 4194304;         // 1M f32
    float* h       = invS    + 1048576;         // 4M f32

    // bf16 conversions
    cvt_bf16<<<4096, 256, 0, stream>>>(x, xb);
    P5 p5;
    p5.in[0] = Wq; p5.in[1] = Wk; p5.in[2] = Wv; p5.in[3] = W1; p5.in[4] = W2;
    p5.out[0] = Wqb; p5.out[1] = Wkb; p5.out[2] = Wvb; p5.out[3] = W1b; p5.out[4] = W2b;
    cvt_bf16_5<<<5120, 256, 0, stream>>>(p5);

    // projections: Q (scaled 1/8), K head-major; V d-major via swapped operands
    gemm_bt<0><<<dim3(16, 32), 256, 0, stream>>>(xb, Wqb, nullptr, Qh, 0.125f);
    gemm_bt<0><<<dim3(16, 32), 256, 0, stream>>>(xb, Wkb, nullptr, Kh, 1.0f);
    gemm_bt<1><<<dim3(64, 8),  256, 0, stream>>>(Wvb, xb, nullptr, Vt, 1.0f);

    // sign masks
    rowmask_bf<<<256, 256, 0, stream>>>(Kh, km);
    rowmask_bf<<<256, 256, 0, stream>>>(Qh, qm);

    // softmax over z (partial exp-sums, combine, apply + PV)
    attn_pass1<<<dim3(16, 16, 4), 256, 0, stream>>>(Qh, Kh, km, partial);
    sum_inv<<<1024, 256, 0, stream>>>(partial, invS);
    attn_pass2<<<dim3(16, 64), 256, 0, stream>>>(Qh, Kh, Vt, km, qm, invS, pad, out);

    // h = LN(x + attn)  (+ bf16 copy for FFN)
    ln_kernel<<<4096, 256, 0, stream>>>(x, out, g1, be1, pad, 0, h, hb);

    // FFN
    gemm_bt<2><<<dim3(16, 32), 256, 0, stream>>>(hb,   W1b, b1, ff1b, 1.0f);
    gemm_bt<3><<<dim3(16, 32), 256, 0, stream>>>(ff1b, W2b, b2, out,  1.0f);

    // out = LN(ff*valid + h) * valid   (in-place over d_out)
    ln_kernel<<<4096, 256, 0, stream>>>(out, h, g2, be2, pad, 1, out, nullptr);
}

// Round 4
// 223.097 us; speedup vs baseline: 10.5579x; 1.0585x over previous
//
#include <hip/hip_runtime.h>
#include <math.h>

typedef unsigned short u16;
typedef unsigned char  u8;
typedef unsigned int   u32;
typedef __attribute__((ext_vector_type(8))) short bf16x8;
typedef __attribute__((ext_vector_type(4))) float f32x4;

#define NSEQ   1024
#define DMODEL 1024
#define ZTOT   64

typedef const __attribute__((address_space(1))) void* gp1;
typedef __attribute__((address_space(3))) void* lp3;

__device__ __forceinline__ void gload16(const void* g, void* l) {
    __builtin_amdgcn_global_load_lds((gp1)g, (lp3)l, 16, 0, 0);
}

__device__ __forceinline__ u16 f2bf(float f) {
    u32 u = __builtin_bit_cast(u32, f);
    return (u16)((u + 0x7FFFu + ((u >> 16) & 1u)) >> 16);
}

// HW packed f32->bf16 (RNE), 2 values -> 1 dword
__device__ __forceinline__ u32 cvt_pk_bf16(float a, float b) {
    u32 r;
    asm("v_cvt_pk_bf16_f32 %0, %1, %2" : "=v"(r) : "v"(a), "v"(b));
    return r;
}

// ---------------------------------------------------------------------------
// fp32 -> bf16 elementwise
// ---------------------------------------------------------------------------
__launch_bounds__(256)
__global__ void cvt_bf16(const float* __restrict__ in, u16* __restrict__ out) {
    int i = (blockIdx.x * 256 + threadIdx.x) * 4;
    float4 v = *(const float4*)(in + i);
    uint2 o;
    o.x = cvt_pk_bf16(v.x, v.y);
    o.y = cvt_pk_bf16(v.z, v.w);
    *(uint2*)(out + i) = o;
}

struct P5 { const float* in[5]; u16* out[5]; };
__launch_bounds__(256)
__global__ void cvt_bf16_5(P5 p) {
    int which = blockIdx.x >> 10;
    int blk   = blockIdx.x & 1023;
    int i = (blk * 256 + threadIdx.x) * 4;
    float4 v = *(const float4*)(p.in[which] + i);
    uint2 o;
    o.x = cvt_pk_bf16(v.x, v.y);
    o.y = cvt_pk_bf16(v.z, v.w);
    *(uint2*)(p.out[which] + i) = o;
}

// sign(sum |row|) over 64 bf16 -> 0/1
__launch_bounds__(256)
__global__ void rowmask_bf(const u16* __restrict__ T, float* __restrict__ out) {
    int r = blockIdx.x * 256 + threadIdx.x;
    const uint4* p = (const uint4*)(T + (size_t)r * 64);
    u32 acc = 0;
    #pragma unroll
    for (int i = 0; i < 8; i++) {
        uint4 q = p[i];
        acc |= (q.x | q.y | q.z | q.w) & 0x7fff7fffu;
    }
    out[r] = acc ? 1.f : 0.f;
}

// ---------------------------------------------------------------------------
// bf16 MFMA GEMM, D[r,c] = sum_k A[r,k]*B[c,k]   (K = 1024)
// BM=128, BN=64, BK=64; double-buffered staging; 4 waves 64x32 each
// ---------------------------------------------------------------------------
template <int MODE>
__launch_bounds__(256)
__global__ void gemm_bt(const u16* __restrict__ A, const u16* __restrict__ B,
                        const float* __restrict__ bias, void* __restrict__ outp,
                        float scale)
{
    __shared__ __align__(16) u16 lA[2][128 * 64];
    __shared__ __align__(16) u16 lB[2][64 * 64];
    const int tid = threadIdx.x, lane = tid & 63, w = tid >> 6;
    const int frow = lane & 15, koct = lane >> 4;
    const int col0 = blockIdx.x * 64, row0 = blockIdx.y * 128;
    const int wrow = (w >> 1) * 64, wcol = (w & 1) * 32;
    f32x4 acc[4][2] = {};

    auto stage = [&](int buf, int k0) {
        #pragma unroll
        for (int i = 0; i < 4; i++) {
            int p = tid + i * 256;
            int row = p >> 3, sl = p & 7, ssl = sl ^ (row & 7);
            gload16(A + (size_t)(row0 + row) * 1024 + k0 + ssl * 8, (char*)lA[buf] + p * 16);
        }
        #pragma unroll
        for (int i = 0; i < 2; i++) {
            int p = tid + i * 256;
            int row = p >> 3, sl = p & 7, ssl = sl ^ (row & 7);
            gload16(B + (size_t)(col0 + row) * 1024 + k0 + ssl * 8, (char*)lB[buf] + p * 16);
        }
    };

    stage(0, 0);
    __syncthreads();
    int buf = 0;
    for (int k0 = 0; k0 < 1024; k0 += 64) {
        if (k0 + 64 < 1024) stage(buf ^ 1, k0 + 64);
        #pragma unroll
        for (int ks = 0; ks < 2; ks++) {
            bf16x8 af[4], bf2[2];
            #pragma unroll
            for (int i = 0; i < 4; i++) {
                int r = wrow + i * 16 + frow;
                int sl = (ks * 4 + koct) ^ (r & 7);
                af[i] = *(const bf16x8*)((const char*)lA[buf] + r * 128 + sl * 16);
            }
            #pragma unroll
            for (int j = 0; j < 2; j++) {
                int r = wcol + j * 16 + frow;
                int sl = (ks * 4 + koct) ^ (r & 7);
                bf2[j] = *(const bf16x8*)((const char*)lB[buf] + r * 128 + sl * 16);
            }
            #pragma unroll
            for (int i = 0; i < 4; i++)
                #pragma unroll
                for (int j = 0; j < 2; j++)
                    acc[i][j] = __builtin_amdgcn_mfma_f32_16x16x32_bf16(af[i], bf2[j], acc[i][j], 0, 0, 0);
        }
        __syncthreads();
        buf ^= 1;
    }

    #pragma unroll
    for (int i = 0; i < 4; i++) {
        #pragma unroll
        for (int j = 0; j < 2; j++) {
            #pragma unroll
            for (int q = 0; q < 4; q++) {
                int r = row0 + wrow + i * 16 + koct * 4 + q;
                int c = col0 + wcol + j * 16 + frow;
                float v = acc[i][j][q];
                if constexpr (MODE == 0) {
                    v *= scale;
                    ((u16*)outp)[(size_t)((c >> 6) * 4 + (r >> 10)) * 65536 +
                                 (size_t)(r & 1023) * 64 + (c & 63)] = f2bf(v);
                } else if constexpr (MODE == 1) {
                    ((u16*)outp)[(size_t)((r >> 6) * 4 + (c >> 10)) * 65536 +
                                 (size_t)(r & 63) * 1024 + (c & 1023)] = f2bf(v);
                } else if constexpr (MODE == 2) {
                    v += bias[c];
                    v = fmaxf(v, 0.f);
                    ((u16*)outp)[(size_t)r * 1024 + c] = f2bf(v);
                } else {
                    v += bias[c];
                    ((float*)outp)[(size_t)r * 1024 + c] = v;
                }
            }
        }
    }
}

// ---------------------------------------------------------------------------
// Pass 1: partial[zg][n][m] = sum_{z in zg*16..+16} exp(s_znm) * km01(z,m)
// Swapped-operand MFMA: D[m-row][n-col] -> per lane: n fixed, m q-consecutive
// => km float4 loads, partial float4 stores.
// ---------------------------------------------------------------------------
__launch_bounds__(256)
__global__ void attn_pass1(const u16* __restrict__ Qh, const u16* __restrict__ Kh,
                           const float* __restrict__ km, float* __restrict__ partial)
{
    __shared__ __align__(16) u16 lQ[2][64 * 64];
    __shared__ __align__(16) u16 lK[2][64 * 64];
    const int tid = threadIdx.x, lane = tid & 63, w = tid >> 6;
    const int frow = lane & 15, koct = lane >> 4;
    const int m0 = blockIdx.x * 64, n0 = blockIdx.y * 64, zg = blockIdx.z;
    const int wn = (w >> 1) * 32, wm = (w & 1) * 32;
    f32x4 ssum[2][2] = {};

    auto stage = [&](int buf, int z) {
        #pragma unroll
        for (int i = 0; i < 2; i++) {
            int p = tid + i * 256;
            int row = p >> 3, sl = p & 7, ssl = sl ^ (row & 7);
            gload16(Qh + (size_t)(z * NSEQ + n0 + row) * 64 + ssl * 8, (char*)lQ[buf] + p * 16);
            gload16(Kh + (size_t)(z * NSEQ + m0 + row) * 64 + ssl * 8, (char*)lK[buf] + p * 16);
        }
    };

    const int z0 = zg * 16;
    stage(0, z0);
    __syncthreads();
    int buf = 0;
    for (int zi = 0; zi < 16; zi++) {
        const int z = z0 + zi;
        if (zi < 15) stage(buf ^ 1, z + 1);
        f32x4 s[2][2] = {};   // s[i][j]: D[m-row][n-col], n = wn+i*16+frow, m = wm+j*16+koct*4+q
        #pragma unroll
        for (int ks = 0; ks < 2; ks++) {
            bf16x8 a[2], b2[2];
            #pragma unroll
            for (int i = 0; i < 2; i++) {
                int r = wn + i * 16 + frow;
                int sl = (ks * 4 + koct) ^ (r & 7);
                a[i] = *(const bf16x8*)((const char*)lQ[buf] + r * 128 + sl * 16);
            }
            #pragma unroll
            for (int j = 0; j < 2; j++) {
                int r = wm + j * 16 + frow;
                int sl = (ks * 4 + koct) ^ (r & 7);
                b2[j] = *(const bf16x8*)((const char*)lK[buf] + r * 128 + sl * 16);
            }
            #pragma unroll
            for (int i = 0; i < 2; i++)
                #pragma unroll
                for (int j = 0; j < 2; j++)
                    s[i][j] = __builtin_amdgcn_mfma_f32_16x16x32_bf16(b2[j], a[i], s[i][j], 0, 0, 0);
        }
        #pragma unroll
        for (int j = 0; j < 2; j++) {
            f32x4 km4 = *(const f32x4*)(km + z * NSEQ + m0 + wm + j * 16 + koct * 4);
            #pragma unroll
            for (int i = 0; i < 2; i++)
                #pragma unroll
                for (int q = 0; q < 4; q++)
                    ssum[i][j][q] += __expf(s[i][j][q]) * km4[q];
        }
        __syncthreads();
        buf ^= 1;
    }
    #pragma unroll
    for (int i = 0; i < 2; i++)
        #pragma unroll
        for (int j = 0; j < 2; j++) {
            int ng = n0 + wn + i * 16 + frow;
            int mg = m0 + wm + j * 16 + koct * 4;
            *(f32x4*)(partial + (size_t)zg * 1048576 + (size_t)ng * NSEQ + mg) = ssum[i][j];
        }
}

// invS = 1 / (p0+p1+p2+p3)
__launch_bounds__(256)
__global__ void sum_inv(const float* __restrict__ p, float* __restrict__ invS) {
    int i = (blockIdx.x * 256 + threadIdx.x) * 4;
    float4 a = *(const float4*)(p + i);
    float4 b = *(const float4*)(p + 1048576 + i);
    float4 c = *(const float4*)(p + 2097152 + i);
    float4 d = *(const float4*)(p + 3145728 + i);
    float4 r;
    float s;
    s = a.x + b.x + c.x + d.x; r.x = s > 0.f ? 1.f / s : 0.f;
    s = a.y + b.y + c.y + d.y; r.y = s > 0.f ? 1.f / s : 0.f;
    s = a.z + b.z + c.z + d.z; r.z = s > 0.f ? 1.f / s : 0.f;
    s = a.w + b.w + c.w + d.w; r.w = s > 0.f ? 1.f / s : 0.f;
    *(float4*)(invS + i) = r;
}

// ---------------------------------------------------------------------------
// Pass 2: per z, out[z,n,:] = sum_m (exp(s)*km*invS) V[m,:]
// Swapped-operand score MFMA: per lane n fixed, m q-consecutive ->
// invS/km float4 loads, cvt_pk_bf16 pairs, ds_write_b64 into lP.
// ---------------------------------------------------------------------------
__launch_bounds__(256)
__global__ void attn_pass2(const u16* __restrict__ Qh, const u16* __restrict__ Kh,
                           const u16* __restrict__ Vt, const float* __restrict__ km,
                           const float* __restrict__ qm, const float* __restrict__ invS,
                           const u8* __restrict__ pad, float* __restrict__ attn)
{
    __shared__ __align__(16) u16 lK[2][64 * 64];
    __shared__ __align__(16) u16 lV[2][64 * 64];   // Vt tile: [d][m]
    __shared__ __align__(16) u16 lP[64 * 64];
    const int tid = threadIdx.x, lane = tid & 63, w = tid >> 6;
    const int frow = lane & 15, koct = lane >> 4;
    const int z = blockIdx.y, n0 = blockIdx.x * 64;
    const int hh = z >> 2, bb = z & 3;
    const int wrow = w * 16;
    const int nl_row = wrow + frow;          // this lane's P row (fixed)
    const size_t inv_base = (size_t)(n0 + nl_row) * NSEQ;

    // Q fragments: loop-invariant, straight from global (L2-hot)
    bf16x8 aq[2];
    #pragma unroll
    for (int ks = 0; ks < 2; ks++)
        aq[ks] = *(const bf16x8*)(Qh + (size_t)(z * NSEQ + n0 + nl_row) * 64 + ks * 32 + koct * 8);

    auto stage = [&](int buf, int m0) {
        #pragma unroll
        for (int i = 0; i < 2; i++) {
            int p = tid + i * 256;
            int row = p >> 3, sl = p & 7, ssl = sl ^ (row & 7);
            gload16(Kh + (size_t)(z * NSEQ + m0 + row) * 64 + ssl * 8, (char*)lK[buf] + p * 16);
            gload16(Vt + (size_t)z * 65536 + (size_t)row * 1024 + m0 + ssl * 8, (char*)lV[buf] + p * 16);
        }
    };

    f32x4 oacc[4] = {};
    stage(0, 0);
    __syncthreads();
    int buf = 0;

    for (int mt = 0; mt < 16; mt++) {
        const int m0 = mt * 64;
        if (mt < 15) stage(buf ^ 1, m0 + 64);
        // swapped scores: s[j] = D[m-row][n-col]; lane: n = nl_row, m = j*16+koct*4+q
        f32x4 s[4] = {};
        #pragma unroll
        for (int ks = 0; ks < 2; ks++) {
            bf16x8 kb[4];
            #pragma unroll
            for (int j = 0; j < 4; j++) {
                int r = j * 16 + frow;
                int sl = (ks * 4 + koct) ^ (r & 7);
                kb[j] = *(const bf16x8*)((const char*)lK[buf] + r * 128 + sl * 16);
            }
            #pragma unroll
            for (int j = 0; j < 4; j++)
                s[j] = __builtin_amdgcn_mfma_f32_16x16x32_bf16(kb[j], aq[ks], s[j], 0, 0, 0);
        }
        // P = exp(s)*km*invS -> bf16 pairs -> lP[nl_row][m] (8B per j, swizzled slot)
        #pragma unroll
        for (int j = 0; j < 4; j++) {
            int mg = m0 + j * 16 + koct * 4;
            f32x4 km4 = *(const f32x4*)(km + z * NSEQ + mg);
            f32x4 iv4 = *(const f32x4*)(invS + inv_base + mg);
            float p0 = __expf(s[j][0]) * km4[0] * iv4[0];
            float p1 = __expf(s[j][1]) * km4[1] * iv4[1];
            float p2 = __expf(s[j][2]) * km4[2] * iv4[2];
            float p3 = __expf(s[j][3]) * km4[3] * iv4[3];
            uint2 pk;
            pk.x = cvt_pk_bf16(p0, p1);
            pk.y = cvt_pk_bf16(p2, p3);
            int slot = (j * 2 + (koct >> 1)) ^ (nl_row & 7);
            *(uint2*)((char*)lP + nl_row * 128 + slot * 16 + (koct & 1) * 8) = pk;
        }
        // PV: A = my P stripe, B = Vt rows (d-major)
        #pragma unroll
        for (int ks = 0; ks < 2; ks++) {
            int sl = (ks * 4 + koct) ^ (nl_row & 7);
            bf16x8 pa = *(const bf16x8*)((const char*)lP + nl_row * 128 + sl * 16);
            bf16x8 vb[4];
            #pragma unroll
            for (int dj = 0; dj < 4; dj++) {
                int rr = dj * 16 + frow;
                int sv = (ks * 4 + koct) ^ (rr & 7);
                vb[dj] = *(const bf16x8*)((const char*)lV[buf] + rr * 128 + sv * 16);
            }
            #pragma unroll
            for (int dj = 0; dj < 4; dj++)
                oacc[dj] = __builtin_amdgcn_mfma_f32_16x16x32_bf16(pa, vb[dj], oacc[dj], 0, 0, 0);
        }
        __syncthreads();
        buf ^= 1;
    }

    #pragma unroll
    for (int q = 0; q < 4; q++) {
        int ns = n0 + wrow + koct * 4 + q;
        float f = qm[z * NSEQ + ns] * (pad[bb * NSEQ + ns] ? 0.f : 1.f);
        #pragma unroll
        for (int dj = 0; dj < 4; dj++) {
            int d = dj * 16 + frow;
            attn[(size_t)(bb * NSEQ + ns) * DMODEL + hh * 64 + d] = oacc[dj][q] * f;
        }
    }
}

// ---------------------------------------------------------------------------
// LayerNorm over last dim (1024), one block per row.
// ---------------------------------------------------------------------------
__launch_bounds__(256)
__global__ void ln_kernel(const float* __restrict__ A, const float* __restrict__ Bv,
                          const float* __restrict__ g, const float* __restrict__ beta,
                          const u8* __restrict__ pad, int mode,
                          float* __restrict__ out, u16* __restrict__ outb)
{
    const int row = blockIdx.x, tid = threadIdx.x;
    const int lane = tid & 63, wv = tid >> 6;
    const float valid = pad[row] ? 0.f : 1.f;
    __shared__ float red[4];

    float4 va = *(const float4*)(A + (size_t)row * 1024 + tid * 4);
    float4 vb = *(const float4*)(Bv + (size_t)row * 1024 + tid * 4);
    float v[4];
    if (mode == 0) {
        v[0] = va.x + vb.x; v[1] = va.y + vb.y; v[2] = va.z + vb.z; v[3] = va.w + vb.w;
    } else {
        v[0] = va.x * valid + vb.x; v[1] = va.y * valid + vb.y;
        v[2] = va.z * valid + vb.z; v[3] = va.w * valid + vb.w;
    }
    float s = v[0] + v[1] + v[2] + v[3];
    #pragma unroll
    for (int off = 32; off > 0; off >>= 1) s += __shfl_down(s, off, 64);
    if (lane == 0) red[wv] = s;
    __syncthreads();
    float mean = (red[0] + red[1] + red[2] + red[3]) * (1.f / 1024.f);
    float sq = 0.f;
    #pragma unroll
    for (int k = 0; k < 4; k++) { float d = v[k] - mean; sq += d * d; }
    __syncthreads();
    #pragma unroll
    for (int off = 32; off > 0; off >>= 1) sq += __shfl_down(sq, off, 64);
    if (lane == 0) red[wv] = sq;
    __syncthreads();
    float var = (red[0] + red[1] + red[2] + red[3]) * (1.f / 1024.f);
    float rstd = rsqrtf(var + 1e-5f);
    float osc = (mode == 0) ? 1.f : valid;
    #pragma unroll
    for (int k = 0; k < 4; k++) {
        int c = tid * 4 + k;
        float o = ((v[k] - mean) * rstd * g[c] + beta[c]) * osc;
        out[(size_t)row * 1024 + c] = o;
        if (outb) outb[(size_t)row * 1024 + c] = f2bf(o);
    }
}

// ---------------------------------------------------------------------------
extern "C" void kernel_launch(void* const* d_in, const int* in_sizes, int n_in,
                              void* d_out, int out_size, void* d_ws, size_t ws_size,
                              hipStream_t stream)
{
    const float* x   = (const float*)d_in[0];
    const u8*    pad = (const u8*)d_in[1];
    const float* Wq  = (const float*)d_in[2];
    const float* Wk  = (const float*)d_in[3];
    const float* Wv  = (const float*)d_in[4];
    const float* W1  = (const float*)d_in[5];
    const float* b1  = (const float*)d_in[6];
    const float* W2  = (const float*)d_in[7];
    const float* b2  = (const float*)d_in[8];
    const float* g1  = (const float*)d_in[9];
    const float* be1 = (const float*)d_in[10];
    const float* g2  = (const float*)d_in[11];
    const float* be2 = (const float*)d_in[12];
    float* out = (float*)d_out;

    // workspace (~99 MB)
    u16* xb   = (u16*)d_ws;
    u16* Wqb  = xb   + 4194304;
    u16* Wkb  = Wqb  + 1048576;
    u16* Wvb  = Wkb  + 1048576;
    u16* W1b  = Wvb  + 1048576;
    u16* W2b  = W1b  + 1048576;
    u16* Qh   = W2b  + 1048576;        // [z][n][dh]
    u16* Kh   = Qh   + 4194304;        // [z][n][dh]
    u16* Vt   = Kh   + 4194304;        // [z][dh][n]
    u16* hb   = Vt   + 4194304;
    u16* ff1b = hb   + 4194304;
    float* km      = (float*)(ff1b + 4194304);
    float* qm      = km      + 65536;
    float* partial = qm      + 65536;           // 4M f32
    float* invS    = partial + 4194304;         // 1M f32
    float* h       = invS    + 1048576;         // 4M f32

    cvt_bf16<<<4096, 256, 0, stream>>>(x, xb);
    P5 p5;
    p5.in[0] = Wq; p5.in[1] = Wk; p5.in[2] = Wv; p5.in[3] = W1; p5.in[4] = W2;
    p5.out[0] = Wqb; p5.out[1] = Wkb; p5.out[2] = Wvb; p5.out[3] = W1b; p5.out[4] = W2b;
    cvt_bf16_5<<<5120, 256, 0, stream>>>(p5);

    gemm_bt<0><<<dim3(16, 32), 256, 0, stream>>>(xb, Wqb, nullptr, Qh, 0.125f);
    gemm_bt<0><<<dim3(16, 32), 256, 0, stream>>>(xb, Wkb, nullptr, Kh, 1.0f);
    gemm_bt<1><<<dim3(64, 8),  256, 0, stream>>>(Wvb, xb, nullptr, Vt, 1.0f);

    rowmask_bf<<<256, 256, 0, stream>>>(Kh, km);
    rowmask_bf<<<256, 256, 0, stream>>>(Qh, qm);

    attn_pass1<<<dim3(16, 16, 4), 256, 0, stream>>>(Qh, Kh, km, partial);
    sum_inv<<<1024, 256, 0, stream>>>(partial, invS);
    attn_pass2<<<dim3(16, 64), 256, 0, stream>>>(Qh, Kh, Vt, km, qm, invS, pad, out);

    ln_kernel<<<4096, 256, 0, stream>>>(x, out, g1, be1, pad, 0, h, hb);

    gemm_bt<2><<<dim3(16, 32), 256, 0, stream>>>(hb,   W1b, b1, ff1b, 1.0f);
    gemm_bt<3><<<dim3(16, 32), 256, 0, stream>>>(ff1b, W2b, b2, out,  1.0f);

    ln_kernel<<<4096, 256, 0, stream>>>(out, h, g2, be2, pad, 1, out, nullptr);
}

// Round 5
// 211.225 us; speedup vs baseline: 11.1513x; 1.0562x over previous
//
#include <hip/hip_runtime.h>
#include <math.h>

typedef unsigned short u16;
typedef unsigned char  u8;
typedef unsigned int   u32;
typedef __attribute__((ext_vector_type(8))) short bf16x8;
typedef __attribute__((ext_vector_type(4))) float f32x4;

#define NSEQ   1024
#define DMODEL 1024
#define ZTOT   64
#define LOG2E  1.4426950408889634f

typedef const __attribute__((address_space(1))) void* gp1;
typedef __attribute__((address_space(3))) void* lp3;

__device__ __forceinline__ void gload16(const void* g, void* l) {
    __builtin_amdgcn_global_load_lds((gp1)g, (lp3)l, 16, 0, 0);
}

__device__ __forceinline__ u16 f2bf(float f) {
    u32 u = __builtin_bit_cast(u32, f);
    return (u16)((u + 0x7FFFu + ((u >> 16) & 1u)) >> 16);
}

// HW packed f32->bf16 (RNE), 2 values -> 1 dword
__device__ __forceinline__ u32 cvt_pk_bf16(float a, float b) {
    u32 r;
    asm("v_cvt_pk_bf16_f32 %0, %1, %2" : "=v"(r) : "v"(a), "v"(b));
    return r;
}

// ---------------------------------------------------------------------------
// fp32 -> bf16 elementwise
// ---------------------------------------------------------------------------
__launch_bounds__(256)
__global__ void cvt_bf16(const float* __restrict__ in, u16* __restrict__ out) {
    int i = (blockIdx.x * 256 + threadIdx.x) * 4;
    float4 v = *(const float4*)(in + i);
    uint2 o;
    o.x = cvt_pk_bf16(v.x, v.y);
    o.y = cvt_pk_bf16(v.z, v.w);
    *(uint2*)(out + i) = o;
}

struct P5 { const float* in[5]; u16* out[5]; };
__launch_bounds__(256)
__global__ void cvt_bf16_5(P5 p) {
    int which = blockIdx.x >> 10;
    int blk   = blockIdx.x & 1023;
    int i = (blk * 256 + threadIdx.x) * 4;
    float4 v = *(const float4*)(p.in[which] + i);
    uint2 o;
    o.x = cvt_pk_bf16(v.x, v.y);
    o.y = cvt_pk_bf16(v.z, v.w);
    *(uint2*)(p.out[which] + i) = o;
}

// sign(sum |row|) over 64 bf16 -> 0/1
__launch_bounds__(256)
__global__ void rowmask_bf(const u16* __restrict__ T, float* __restrict__ out) {
    int r = blockIdx.x * 256 + threadIdx.x;
    const uint4* p = (const uint4*)(T + (size_t)r * 64);
    u32 acc = 0;
    #pragma unroll
    for (int i = 0; i < 8; i++) {
        uint4 q = p[i];
        acc |= (q.x | q.y | q.z | q.w) & 0x7fff7fffu;
    }
    out[r] = acc ? 1.f : 0.f;
}

// ---------------------------------------------------------------------------
// bf16 MFMA GEMM, D[r,c] = sum_k A[r,k]*B[c,k]   (K = 1024)
// BM=128, BN=64, BK=64; double-buffered staging; 4 waves 64x32 each
// MODE 0: head-major bf16 out (proj Q/K), *scale
// MODE 1: Vt out [z][dh][n] bf16, multiplied by km[z][token]
// MODE 2: +bias, relu, bf16 out row-major
// MODE 3: +bias, f32 out row-major
// ---------------------------------------------------------------------------
template <int MODE>
__launch_bounds__(256)
__global__ void gemm_bt(const u16* __restrict__ A, const u16* __restrict__ B,
                        const float* __restrict__ bias, void* __restrict__ outp,
                        float scale, const float* __restrict__ kmp)
{
    __shared__ __align__(16) u16 lA[2][128 * 64];
    __shared__ __align__(16) u16 lB[2][64 * 64];
    const int tid = threadIdx.x, lane = tid & 63, w = tid >> 6;
    const int frow = lane & 15, koct = lane >> 4;
    const int col0 = blockIdx.x * 64, row0 = blockIdx.y * 128;
    const int wrow = (w >> 1) * 64, wcol = (w & 1) * 32;
    f32x4 acc[4][2] = {};

    auto stage = [&](int buf, int k0) {
        #pragma unroll
        for (int i = 0; i < 4; i++) {
            int p = tid + i * 256;
            int row = p >> 3, sl = p & 7, ssl = sl ^ (row & 7);
            gload16(A + (size_t)(row0 + row) * 1024 + k0 + ssl * 8, (char*)lA[buf] + p * 16);
        }
        #pragma unroll
        for (int i = 0; i < 2; i++) {
            int p = tid + i * 256;
            int row = p >> 3, sl = p & 7, ssl = sl ^ (row & 7);
            gload16(B + (size_t)(col0 + row) * 1024 + k0 + ssl * 8, (char*)lB[buf] + p * 16);
        }
    };

    stage(0, 0);
    __syncthreads();
    int buf = 0;
    for (int k0 = 0; k0 < 1024; k0 += 64) {
        if (k0 + 64 < 1024) stage(buf ^ 1, k0 + 64);
        __builtin_amdgcn_s_setprio(1);
        #pragma unroll
        for (int ks = 0; ks < 2; ks++) {
            bf16x8 af[4], bf2[2];
            #pragma unroll
            for (int i = 0; i < 4; i++) {
                int r = wrow + i * 16 + frow;
                int sl = (ks * 4 + koct) ^ (r & 7);
                af[i] = *(const bf16x8*)((const char*)lA[buf] + r * 128 + sl * 16);
            }
            #pragma unroll
            for (int j = 0; j < 2; j++) {
                int r = wcol + j * 16 + frow;
                int sl = (ks * 4 + koct) ^ (r & 7);
                bf2[j] = *(const bf16x8*)((const char*)lB[buf] + r * 128 + sl * 16);
            }
            #pragma unroll
            for (int i = 0; i < 4; i++)
                #pragma unroll
                for (int j = 0; j < 2; j++)
                    acc[i][j] = __builtin_amdgcn_mfma_f32_16x16x32_bf16(af[i], bf2[j], acc[i][j], 0, 0, 0);
        }
        __builtin_amdgcn_s_setprio(0);
        __syncthreads();
        buf ^= 1;
    }

    #pragma unroll
    for (int i = 0; i < 4; i++) {
        #pragma unroll
        for (int j = 0; j < 2; j++) {
            #pragma unroll
            for (int q = 0; q < 4; q++) {
                int r = row0 + wrow + i * 16 + koct * 4 + q;
                int c = col0 + wcol + j * 16 + frow;
                float v = acc[i][j][q];
                if constexpr (MODE == 0) {
                    v *= scale;
                    ((u16*)outp)[(size_t)((c >> 6) * 4 + (r >> 10)) * 65536 +
                                 (size_t)(r & 1023) * 64 + (c & 63)] = f2bf(v);
                } else if constexpr (MODE == 1) {
                    // r = channel, c = token; multiply km[z][token]
                    int zz = (r >> 6) * 4 + (c >> 10);
                    v *= kmp[(size_t)zz * 1024 + (c & 1023)];
                    ((u16*)outp)[(size_t)zz * 65536 +
                                 (size_t)(r & 63) * 1024 + (c & 1023)] = f2bf(v);
                } else if constexpr (MODE == 2) {
                    v += bias[c];
                    v = fmaxf(v, 0.f);
                    ((u16*)outp)[(size_t)r * 1024 + c] = f2bf(v);
                } else {
                    v += bias[c];
                    ((float*)outp)[(size_t)r * 1024 + c] = v;
                }
            }
        }
    }
}

// ---------------------------------------------------------------------------
// Pass 1: partial[zg][n][m] = sum_{z in zg*16..+16} exp2(s'_znm) * km01(z,m)
// (Q pre-scaled by log2e so exp2 == exp of raw scores.)
// Swapped-operand MFMA: per lane n fixed, m q-consecutive.
// ---------------------------------------------------------------------------
__launch_bounds__(256)
__global__ void attn_pass1(const u16* __restrict__ Qh, const u16* __restrict__ Kh,
                           const float* __restrict__ km, float* __restrict__ partial)
{
    __shared__ __align__(16) u16 lQ[2][64 * 64];
    __shared__ __align__(16) u16 lK[2][64 * 64];
    const int tid = threadIdx.x, lane = tid & 63, w = tid >> 6;
    const int frow = lane & 15, koct = lane >> 4;
    const int m0 = blockIdx.x * 64, n0 = blockIdx.y * 64, zg = blockIdx.z;
    const int wn = (w >> 1) * 32, wm = (w & 1) * 32;
    f32x4 ssum[2][2] = {};

    auto stage = [&](int buf, int z) {
        #pragma unroll
        for (int i = 0; i < 2; i++) {
            int p = tid + i * 256;
            int row = p >> 3, sl = p & 7, ssl = sl ^ (row & 7);
            gload16(Qh + (size_t)(z * NSEQ + n0 + row) * 64 + ssl * 8, (char*)lQ[buf] + p * 16);
            gload16(Kh + (size_t)(z * NSEQ + m0 + row) * 64 + ssl * 8, (char*)lK[buf] + p * 16);
        }
    };

    const int z0 = zg * 16;
    stage(0, z0);
    __syncthreads();
    int buf = 0;
    for (int zi = 0; zi < 16; zi++) {
        const int z = z0 + zi;
        if (zi < 15) stage(buf ^ 1, z + 1);
        // issue km loads early; consumed after MFMA cluster
        f32x4 km4[2];
        #pragma unroll
        for (int j = 0; j < 2; j++)
            km4[j] = *(const f32x4*)(km + z * NSEQ + m0 + wm + j * 16 + koct * 4);
        f32x4 s[2][2] = {};
        __builtin_amdgcn_s_setprio(1);
        #pragma unroll
        for (int ks = 0; ks < 2; ks++) {
            bf16x8 a[2], b2[2];
            #pragma unroll
            for (int i = 0; i < 2; i++) {
                int r = wn + i * 16 + frow;
                int sl = (ks * 4 + koct) ^ (r & 7);
                a[i] = *(const bf16x8*)((const char*)lQ[buf] + r * 128 + sl * 16);
            }
            #pragma unroll
            for (int j = 0; j < 2; j++) {
                int r = wm + j * 16 + frow;
                int sl = (ks * 4 + koct) ^ (r & 7);
                b2[j] = *(const bf16x8*)((const char*)lK[buf] + r * 128 + sl * 16);
            }
            #pragma unroll
            for (int i = 0; i < 2; i++)
                #pragma unroll
                for (int j = 0; j < 2; j++)
                    s[i][j] = __builtin_amdgcn_mfma_f32_16x16x32_bf16(b2[j], a[i], s[i][j], 0, 0, 0);
        }
        __builtin_amdgcn_s_setprio(0);
        #pragma unroll
        for (int j = 0; j < 2; j++)
            #pragma unroll
            for (int i = 0; i < 2; i++)
                #pragma unroll
                for (int q = 0; q < 4; q++)
                    ssum[i][j][q] += __builtin_amdgcn_exp2f(s[i][j][q]) * km4[j][q];
        __syncthreads();
        buf ^= 1;
    }
    #pragma unroll
    for (int i = 0; i < 2; i++)
        #pragma unroll
        for (int j = 0; j < 2; j++) {
            int ng = n0 + wn + i * 16 + frow;
            int mg = m0 + wm + j * 16 + koct * 4;
            *(f32x4*)(partial + (size_t)zg * 1048576 + (size_t)ng * NSEQ + mg) = ssum[i][j];
        }
}

// invS = 1 / (p0+p1+p2+p3)
__launch_bounds__(256)
__global__ void sum_inv(const float* __restrict__ p, float* __restrict__ invS) {
    int i = (blockIdx.x * 256 + threadIdx.x) * 4;
    float4 a = *(const float4*)(p + i);
    float4 b = *(const float4*)(p + 1048576 + i);
    float4 c = *(const float4*)(p + 2097152 + i);
    float4 d = *(const float4*)(p + 3145728 + i);
    float4 r;
    float s;
    s = a.x + b.x + c.x + d.x; r.x = s > 0.f ? 1.f / s : 0.f;
    s = a.y + b.y + c.y + d.y; r.y = s > 0.f ? 1.f / s : 0.f;
    s = a.z + b.z + c.z + d.z; r.z = s > 0.f ? 1.f / s : 0.f;
    s = a.w + b.w + c.w + d.w; r.w = s > 0.f ? 1.f / s : 0.f;
    *(float4*)(invS + i) = r;
}

// ---------------------------------------------------------------------------
// Pass 2: per z, out[z,n,:] = sum_m (exp2(s')*invS) V'[m,:]   (V' = V*km)
// Swapped-operand score MFMA; invS register-prefetched one m-tile ahead.
// ---------------------------------------------------------------------------
__launch_bounds__(256)
__global__ void attn_pass2(const u16* __restrict__ Qh, const u16* __restrict__ Kh,
                           const u16* __restrict__ Vt,
                           const float* __restrict__ qm, const float* __restrict__ invS,
                           const u8* __restrict__ pad, float* __restrict__ attn)
{
    __shared__ __align__(16) u16 lK[2][64 * 64];
    __shared__ __align__(16) u16 lV[2][64 * 64];   // Vt tile: [d][m]
    __shared__ __align__(16) u16 lP[64 * 64];
    const int tid = threadIdx.x, lane = tid & 63, w = tid >> 6;
    const int frow = lane & 15, koct = lane >> 4;
    const int z = blockIdx.y, n0 = blockIdx.x * 64;
    const int hh = z >> 2, bb = z & 3;
    const int wrow = w * 16;
    const int nl_row = wrow + frow;          // this lane's P row (fixed)
    const size_t inv_base = (size_t)(n0 + nl_row) * NSEQ;

    // Q fragments: loop-invariant, straight from global (L2-hot)
    bf16x8 aq[2];
    #pragma unroll
    for (int ks = 0; ks < 2; ks++)
        aq[ks] = *(const bf16x8*)(Qh + (size_t)(z * NSEQ + n0 + nl_row) * 64 + ks * 32 + koct * 8);

    auto stage = [&](int buf, int m0) {
        #pragma unroll
        for (int i = 0; i < 2; i++) {
            int p = tid + i * 256;
            int row = p >> 3, sl = p & 7, ssl = sl ^ (row & 7);
            gload16(Kh + (size_t)(z * NSEQ + m0 + row) * 64 + ssl * 8, (char*)lK[buf] + p * 16);
            gload16(Vt + (size_t)z * 65536 + (size_t)row * 1024 + m0 + ssl * 8, (char*)lV[buf] + p * 16);
        }
    };

    f32x4 oacc[4] = {};
    f32x4 iv[4];
    #pragma unroll
    for (int j = 0; j < 4; j++)
        iv[j] = *(const f32x4*)(invS + inv_base + j * 16 + koct * 4);
    stage(0, 0);
    __syncthreads();
    int buf = 0;

    for (int mt = 0; mt < 16; mt++) {
        const int m0 = mt * 64;
        if (mt < 15) stage(buf ^ 1, m0 + 64);
        // prefetch next tile's invS (hides L2 latency under MFMAs)
        f32x4 ivn[4];
        if (mt < 15) {
            #pragma unroll
            for (int j = 0; j < 4; j++)
                ivn[j] = *(const f32x4*)(invS + inv_base + m0 + 64 + j * 16 + koct * 4);
        }
        // swapped scores: s[j]; lane: n = nl_row, m = m0 + j*16+koct*4+q
        f32x4 s[4] = {};
        __builtin_amdgcn_s_setprio(1);
        #pragma unroll
        for (int ks = 0; ks < 2; ks++) {
            bf16x8 kb[4];
            #pragma unroll
            for (int j = 0; j < 4; j++) {
                int r = j * 16 + frow;
                int sl = (ks * 4 + koct) ^ (r & 7);
                kb[j] = *(const bf16x8*)((const char*)lK[buf] + r * 128 + sl * 16);
            }
            #pragma unroll
            for (int j = 0; j < 4; j++)
                s[j] = __builtin_amdgcn_mfma_f32_16x16x32_bf16(kb[j], aq[ks], s[j], 0, 0, 0);
        }
        __builtin_amdgcn_s_setprio(0);
        // P = exp2(s)*invS -> bf16 pairs -> lP[nl_row][m]
        #pragma unroll
        for (int j = 0; j < 4; j++) {
            float p0 = __builtin_amdgcn_exp2f(s[j][0]) * iv[j][0];
            float p1 = __builtin_amdgcn_exp2f(s[j][1]) * iv[j][1];
            float p2 = __builtin_amdgcn_exp2f(s[j][2]) * iv[j][2];
            float p3 = __builtin_amdgcn_exp2f(s[j][3]) * iv[j][3];
            uint2 pk;
            pk.x = cvt_pk_bf16(p0, p1);
            pk.y = cvt_pk_bf16(p2, p3);
            int slot = (j * 2 + (koct >> 1)) ^ (nl_row & 7);
            *(uint2*)((char*)lP + nl_row * 128 + slot * 16 + (koct & 1) * 8) = pk;
        }
        // PV: A = my P stripe, B = Vt rows (d-major)
        __builtin_amdgcn_s_setprio(1);
        #pragma unroll
        for (int ks = 0; ks < 2; ks++) {
            int sl = (ks * 4 + koct) ^ (nl_row & 7);
            bf16x8 pa = *(const bf16x8*)((const char*)lP + nl_row * 128 + sl * 16);
            bf16x8 vb[4];
            #pragma unroll
            for (int dj = 0; dj < 4; dj++) {
                int rr = dj * 16 + frow;
                int sv = (ks * 4 + koct) ^ (rr & 7);
                vb[dj] = *(const bf16x8*)((const char*)lV[buf] + rr * 128 + sv * 16);
            }
            #pragma unroll
            for (int dj = 0; dj < 4; dj++)
                oacc[dj] = __builtin_amdgcn_mfma_f32_16x16x32_bf16(pa, vb[dj], oacc[dj], 0, 0, 0);
        }
        __builtin_amdgcn_s_setprio(0);
        __syncthreads();
        buf ^= 1;
        #pragma unroll
        for (int j = 0; j < 4; j++) iv[j] = ivn[j];
    }

    #pragma unroll
    for (int q = 0; q < 4; q++) {
        int ns = n0 + wrow + koct * 4 + q;
        float f = qm[z * NSEQ + ns] * (pad[bb * NSEQ + ns] ? 0.f : 1.f);
        #pragma unroll
        for (int dj = 0; dj < 4; dj++) {
            int d = dj * 16 + frow;
            attn[(size_t)(bb * NSEQ + ns) * DMODEL + hh * 64 + d] = oacc[dj][q] * f;
        }
    }
}

// ---------------------------------------------------------------------------
// LayerNorm over last dim (1024), one block per row.
// ---------------------------------------------------------------------------
__launch_bounds__(256)
__global__ void ln_kernel(const float* __restrict__ A, const float* __restrict__ Bv,
                          const float* __restrict__ g, const float* __restrict__ beta,
                          const u8* __restrict__ pad, int mode,
                          float* __restrict__ out, u16* __restrict__ outb)
{
    const int row = blockIdx.x, tid = threadIdx.x;
    const int lane = tid & 63, wv = tid >> 6;
    const float valid = pad[row] ? 0.f : 1.f;
    __shared__ float red[4];

    float4 va = *(const float4*)(A + (size_t)row * 1024 + tid * 4);
    float4 vb = *(const float4*)(Bv + (size_t)row * 1024 + tid * 4);
    float v[4];
    if (mode == 0) {
        v[0] = va.x + vb.x; v[1] = va.y + vb.y; v[2] = va.z + vb.z; v[3] = va.w + vb.w;
    } else {
        v[0] = va.x * valid + vb.x; v[1] = va.y * valid + vb.y;
        v[2] = va.z * valid + vb.z; v[3] = va.w * valid + vb.w;
    }
    float s = v[0] + v[1] + v[2] + v[3];
    #pragma unroll
    for (int off = 32; off > 0; off >>= 1) s += __shfl_down(s, off, 64);
    if (lane == 0) red[wv] = s;
    __syncthreads();
    float mean = (red[0] + red[1] + red[2] + red[3]) * (1.f / 1024.f);
    float sq = 0.f;
    #pragma unroll
    for (int k = 0; k < 4; k++) { float d = v[k] - mean; sq += d * d; }
    __syncthreads();
    #pragma unroll
    for (int off = 32; off > 0; off >>= 1) sq += __shfl_down(sq, off, 64);
    if (lane == 0) red[wv] = sq;
    __syncthreads();
    float var = (red[0] + red[1] + red[2] + red[3]) * (1.f / 1024.f);
    float rstd = rsqrtf(var + 1e-5f);
    float osc = (mode == 0) ? 1.f : valid;
    #pragma unroll
    for (int k = 0; k < 4; k++) {
        int c = tid * 4 + k;
        float o = ((v[k] - mean) * rstd * g[c] + beta[c]) * osc;
        out[(size_t)row * 1024 + c] = o;
        if (outb) outb[(size_t)row * 1024 + c] = f2bf(o);
    }
}

// ---------------------------------------------------------------------------
extern "C" void kernel_launch(void* const* d_in, const int* in_sizes, int n_in,
                              void* d_out, int out_size, void* d_ws, size_t ws_size,
                              hipStream_t stream)
{
    const float* x   = (const float*)d_in[0];
    const u8*    pad = (const u8*)d_in[1];
    const float* Wq  = (const float*)d_in[2];
    const float* Wk  = (const float*)d_in[3];
    const float* Wv  = (const float*)d_in[4];
    const float* W1  = (const float*)d_in[5];
    const float* b1  = (const float*)d_in[6];
    const float* W2  = (const float*)d_in[7];
    const float* b2  = (const float*)d_in[8];
    const float* g1  = (const float*)d_in[9];
    const float* be1 = (const float*)d_in[10];
    const float* g2  = (const float*)d_in[11];
    const float* be2 = (const float*)d_in[12];
    float* out = (float*)d_out;

    // workspace (~99 MB)
    u16* xb   = (u16*)d_ws;
    u16* Wqb  = xb   + 4194304;
    u16* Wkb  = Wqb  + 1048576;
    u16* Wvb  = Wkb  + 1048576;
    u16* W1b  = Wvb  + 1048576;
    u16* W2b  = W1b  + 1048576;
    u16* Qh   = W2b  + 1048576;        // [z][n][dh]
    u16* Kh   = Qh   + 4194304;        // [z][n][dh]
    u16* Vt   = Kh   + 4194304;        // [z][dh][n]  (pre-multiplied by km)
    u16* hb   = Vt   + 4194304;
    u16* ff1b = hb   + 4194304;
    float* km      = (float*)(ff1b + 4194304);
    float* qm      = km      + 65536;
    float* partial = qm      + 65536;           // 4M f32
    float* invS    = partial + 4194304;         // 1M f32
    float* h       = invS    + 1048576;         // 4M f32

    cvt_bf16<<<4096, 256, 0, stream>>>(x, xb);
    P5 p5;
    p5.in[0] = Wq; p5.in[1] = Wk; p5.in[2] = Wv; p5.in[3] = W1; p5.in[4] = W2;
    p5.out[0] = Wqb; p5.out[1] = Wkb; p5.out[2] = Wvb; p5.out[3] = W1b; p5.out[4] = W2b;
    cvt_bf16_5<<<5120, 256, 0, stream>>>(p5);

    // Q scale folds 1/sqrt(DH) * log2(e): scores land in log2-domain
    gemm_bt<0><<<dim3(16, 32), 256, 0, stream>>>(xb, Wqb, nullptr, Qh, 0.125f * LOG2E, nullptr);
    gemm_bt<0><<<dim3(16, 32), 256, 0, stream>>>(xb, Wkb, nullptr, Kh, 1.0f, nullptr);
    rowmask_bf<<<256, 256, 0, stream>>>(Kh, km);
    rowmask_bf<<<256, 256, 0, stream>>>(Qh, qm);
    // V (d-major) with km folded into the epilogue
    gemm_bt<1><<<dim3(64, 8),  256, 0, stream>>>(Wvb, xb, nullptr, Vt, 1.0f, km);

    attn_pass1<<<dim3(16, 16, 4), 256, 0, stream>>>(Qh, Kh, km, partial);
    sum_inv<<<1024, 256, 0, stream>>>(partial, invS);
    attn_pass2<<<dim3(16, 64), 256, 0, stream>>>(Qh, Kh, Vt, qm, invS, pad, out);

    ln_kernel<<<4096, 256, 0, stream>>>(x, out, g1, be1, pad, 0, h, hb);

    gemm_bt<2><<<dim3(16, 32), 256, 0, stream>>>(hb,   W1b, b1, ff1b, 1.0f, nullptr);
    gemm_bt<3><<<dim3(16, 32), 256, 0, stream>>>(ff1b, W2b, b2, out,  1.0f, nullptr);

    ln_kernel<<<4096, 256, 0, stream>>>(out, h, g2, be2, pad, 1, out, nullptr);
}

// Round 6
// 202.681 us; speedup vs baseline: 11.6213x; 1.0422x over previous
//
#include <hip/hip_runtime.h>
#include <math.h>

typedef unsigned short u16;
typedef unsigned char  u8;
typedef unsigned int   u32;
typedef __attribute__((ext_vector_type(8))) short bf16x8;
typedef __attribute__((ext_vector_type(4))) float f32x4;

#define NSEQ   1024
#define DMODEL 1024
#define ZTOT   64
#define LOG2E  1.4426950408889634f

typedef const __attribute__((address_space(1))) void* gp1;
typedef __attribute__((address_space(3))) void* lp3;

__device__ __forceinline__ void gload16(const void* g, void* l) {
    __builtin_amdgcn_global_load_lds((gp1)g, (lp3)l, 16, 0, 0);
}

__device__ __forceinline__ u16 f2bf(float f) {
    u32 u = __builtin_bit_cast(u32, f);
    return (u16)((u + 0x7FFFu + ((u >> 16) & 1u)) >> 16);
}

// HW packed f32->bf16 (RNE), 2 values -> 1 dword
__device__ __forceinline__ u32 cvt_pk_bf16(float a, float b) {
    u32 r;
    asm("v_cvt_pk_bf16_f32 %0, %1, %2" : "=v"(r) : "v"(a), "v"(b));
    return r;
}

// ---------------------------------------------------------------------------
// fp32 -> bf16 elementwise
// ---------------------------------------------------------------------------
__launch_bounds__(256)
__global__ void cvt_bf16(const float* __restrict__ in, u16* __restrict__ out) {
    int i = (blockIdx.x * 256 + threadIdx.x) * 4;
    float4 v = *(const float4*)(in + i);
    uint2 o;
    o.x = cvt_pk_bf16(v.x, v.y);
    o.y = cvt_pk_bf16(v.z, v.w);
    *(uint2*)(out + i) = o;
}

struct P5 { const float* in[5]; u16* out[5]; };
__launch_bounds__(256)
__global__ void cvt_bf16_5(P5 p) {
    int which = blockIdx.x >> 10;
    int blk   = blockIdx.x & 1023;
    int i = (blk * 256 + threadIdx.x) * 4;
    float4 v = *(const float4*)(p.in[which] + i);
    uint2 o;
    o.x = cvt_pk_bf16(v.x, v.y);
    o.y = cvt_pk_bf16(v.z, v.w);
    *(uint2*)(p.out[which] + i) = o;
}

// sign(sum |row|) over 64 bf16 -> 0/1
__launch_bounds__(256)
__global__ void rowmask_bf(const u16* __restrict__ T, float* __restrict__ out) {
    int r = blockIdx.x * 256 + threadIdx.x;
    const uint4* p = (const uint4*)(T + (size_t)r * 64);
    u32 acc = 0;
    #pragma unroll
    for (int i = 0; i < 8; i++) {
        uint4 q = p[i];
        acc |= (q.x | q.y | q.z | q.w) & 0x7fff7fffu;
    }
    out[r] = acc ? 1.f : 0.f;
}

// Vt[z][dh][tok] &= (km[z][tok] != 0)
__launch_bounds__(256)
__global__ void vt_km(u16* __restrict__ Vt, const float* __restrict__ km) {
    int idx = blockIdx.x * 256 + threadIdx.x;  // uint4 index (8 bf16)
    int e0 = idx * 8;
    int z = e0 >> 16;
    int tok = e0 & 1023;
    float4 ka = *(const float4*)(km + z * 1024 + tok);
    float4 kb = *(const float4*)(km + z * 1024 + tok + 4);
    uint4 v = *(uint4*)(Vt + e0);
    u32 m;
    m = (ka.x != 0.f ? 0x0000FFFFu : 0u) | (ka.y != 0.f ? 0xFFFF0000u : 0u); v.x &= m;
    m = (ka.z != 0.f ? 0x0000FFFFu : 0u) | (ka.w != 0.f ? 0xFFFF0000u : 0u); v.y &= m;
    m = (kb.x != 0.f ? 0x0000FFFFu : 0u) | (kb.y != 0.f ? 0xFFFF0000u : 0u); v.z &= m;
    m = (kb.z != 0.f ? 0x0000FFFFu : 0u) | (kb.w != 0.f ? 0xFFFF0000u : 0u); v.w &= m;
    *(uint4*)(Vt + e0) = v;
}

// ---------------------------------------------------------------------------
// Fused QKV projection GEMM. D[r,c] = sum_k x[r,k]*W[c,k], K=1024.
// BM=128, BN=64, BK=64, dbuf; grid (48, 32): bx>>4 selects {Q, K, V}.
// Q: head-major bf16, * (0.125*log2e). K: head-major. V: transposed [z][dh][tok].
// ---------------------------------------------------------------------------
__launch_bounds__(256)
__global__ void gemm_qkv(const u16* __restrict__ A,
                         const u16* __restrict__ Wq, const u16* __restrict__ Wk,
                         const u16* __restrict__ Wv,
                         u16* __restrict__ Qh, u16* __restrict__ Kh, u16* __restrict__ Vt)
{
    __shared__ __align__(16) u16 lA[2][128 * 64];
    __shared__ __align__(16) u16 lB[2][64 * 64];
    const int tid = threadIdx.x, lane = tid & 63, w = tid >> 6;
    const int frow = lane & 15, koct = lane >> 4;
    const int sel = blockIdx.x >> 4;
    const int col0 = (blockIdx.x & 15) * 64, row0 = blockIdx.y * 128;
    const u16* B = (sel == 0) ? Wq : (sel == 1) ? Wk : Wv;
    const int wrow = (w >> 1) * 64, wcol = (w & 1) * 32;
    f32x4 acc[4][2] = {};

    auto stage = [&](int buf, int k0) {
        #pragma unroll
        for (int i = 0; i < 4; i++) {
            int p = tid + i * 256;
            int row = p >> 3, sl = p & 7, ssl = sl ^ (row & 7);
            gload16(A + (size_t)(row0 + row) * 1024 + k0 + ssl * 8, (char*)lA[buf] + p * 16);
        }
        #pragma unroll
        for (int i = 0; i < 2; i++) {
            int p = tid + i * 256;
            int row = p >> 3, sl = p & 7, ssl = sl ^ (row & 7);
            gload16(B + (size_t)(col0 + row) * 1024 + k0 + ssl * 8, (char*)lB[buf] + p * 16);
        }
    };

    stage(0, 0);
    __syncthreads();
    int buf = 0;
    for (int k0 = 0; k0 < 1024; k0 += 64) {
        if (k0 + 64 < 1024) stage(buf ^ 1, k0 + 64);
        __builtin_amdgcn_s_setprio(1);
        #pragma unroll
        for (int ks = 0; ks < 2; ks++) {
            bf16x8 af[4], bf2[2];
            #pragma unroll
            for (int i = 0; i < 4; i++) {
                int r = wrow + i * 16 + frow;
                int sl = (ks * 4 + koct) ^ (r & 7);
                af[i] = *(const bf16x8*)((const char*)lA[buf] + r * 128 + sl * 16);
            }
            #pragma unroll
            for (int j = 0; j < 2; j++) {
                int r = wcol + j * 16 + frow;
                int sl = (ks * 4 + koct) ^ (r & 7);
                bf2[j] = *(const bf16x8*)((const char*)lB[buf] + r * 128 + sl * 16);
            }
            #pragma unroll
            for (int i = 0; i < 4; i++)
                #pragma unroll
                for (int j = 0; j < 2; j++)
                    acc[i][j] = __builtin_amdgcn_mfma_f32_16x16x32_bf16(af[i], bf2[j], acc[i][j], 0, 0, 0);
        }
        __builtin_amdgcn_s_setprio(0);
        __syncthreads();
        buf ^= 1;
    }

    if (sel < 2) {
        const float scale = (sel == 0) ? 0.125f * LOG2E : 1.0f;
        u16* outp = (sel == 0) ? Qh : Kh;
        #pragma unroll
        for (int i = 0; i < 4; i++)
            #pragma unroll
            for (int j = 0; j < 2; j++)
                #pragma unroll
                for (int q = 0; q < 4; q++) {
                    int r = row0 + wrow + i * 16 + koct * 4 + q;
                    int c = col0 + wcol + j * 16 + frow;
                    float v = acc[i][j][q] * scale;
                    outp[(size_t)((c >> 6) * 4 + (r >> 10)) * 65536 +
                         (size_t)(r & 1023) * 64 + (c & 63)] = f2bf(v);
                }
    } else {
        // Vt[z][dh][tok]: tokens are q-consecutive -> 8B packed stores
        #pragma unroll
        for (int i = 0; i < 4; i++) {
            int r0 = row0 + wrow + i * 16 + koct * 4;   // token base (mult of 4)
            #pragma unroll
            for (int j = 0; j < 2; j++) {
                int c = col0 + wcol + j * 16 + frow;    // channel
                int z = (c >> 6) * 4 + (r0 >> 10);
                uint2 pk;
                pk.x = cvt_pk_bf16(acc[i][j][0], acc[i][j][1]);
                pk.y = cvt_pk_bf16(acc[i][j][2], acc[i][j][3]);
                *(uint2*)(Vt + (size_t)z * 65536 + (size_t)(c & 63) * 1024 + (r0 & 1023)) = pk;
            }
        }
    }
}

// ---------------------------------------------------------------------------
// bf16 MFMA GEMM for FFN. D[r,c] = sum_k A[r,k]*B[c,k]  (K = 1024)
// MODE 2: +bias, relu, bf16 out. MODE 3: +bias, f32 out.
// ---------------------------------------------------------------------------
template <int MODE>
__launch_bounds__(256)
__global__ void gemm_bt(const u16* __restrict__ A, const u16* __restrict__ B,
                        const float* __restrict__ bias, void* __restrict__ outp)
{
    __shared__ __align__(16) u16 lA[2][128 * 64];
    __shared__ __align__(16) u16 lB[2][64 * 64];
    const int tid = threadIdx.x, lane = tid & 63, w = tid >> 6;
    const int frow = lane & 15, koct = lane >> 4;
    const int col0 = blockIdx.x * 64, row0 = blockIdx.y * 128;
    const int wrow = (w >> 1) * 64, wcol = (w & 1) * 32;
    f32x4 acc[4][2] = {};

    auto stage = [&](int buf, int k0) {
        #pragma unroll
        for (int i = 0; i < 4; i++) {
            int p = tid + i * 256;
            int row = p >> 3, sl = p & 7, ssl = sl ^ (row & 7);
            gload16(A + (size_t)(row0 + row) * 1024 + k0 + ssl * 8, (char*)lA[buf] + p * 16);
        }
        #pragma unroll
        for (int i = 0; i < 2; i++) {
            int p = tid + i * 256;
            int row = p >> 3, sl = p & 7, ssl = sl ^ (row & 7);
            gload16(B + (size_t)(col0 + row) * 1024 + k0 + ssl * 8, (char*)lB[buf] + p * 16);
        }
    };

    stage(0, 0);
    __syncthreads();
    int buf = 0;
    for (int k0 = 0; k0 < 1024; k0 += 64) {
        if (k0 + 64 < 1024) stage(buf ^ 1, k0 + 64);
        __builtin_amdgcn_s_setprio(1);
        #pragma unroll
        for (int ks = 0; ks < 2; ks++) {
            bf16x8 af[4], bf2[2];
            #pragma unroll
            for (int i = 0; i < 4; i++) {
                int r = wrow + i * 16 + frow;
                int sl = (ks * 4 + koct) ^ (r & 7);
                af[i] = *(const bf16x8*)((const char*)lA[buf] + r * 128 + sl * 16);
            }
            #pragma unroll
            for (int j = 0; j < 2; j++) {
                int r = wcol + j * 16 + frow;
                int sl = (ks * 4 + koct) ^ (r & 7);
                bf2[j] = *(const bf16x8*)((const char*)lB[buf] + r * 128 + sl * 16);
            }
            #pragma unroll
            for (int i = 0; i < 4; i++)
                #pragma unroll
                for (int j = 0; j < 2; j++)
                    acc[i][j] = __builtin_amdgcn_mfma_f32_16x16x32_bf16(af[i], bf2[j], acc[i][j], 0, 0, 0);
        }
        __builtin_amdgcn_s_setprio(0);
        __syncthreads();
        buf ^= 1;
    }

    #pragma unroll
    for (int i = 0; i < 4; i++)
        #pragma unroll
        for (int j = 0; j < 2; j++)
            #pragma unroll
            for (int q = 0; q < 4; q++) {
                int r = row0 + wrow + i * 16 + koct * 4 + q;
                int c = col0 + wcol + j * 16 + frow;
                float v = acc[i][j][q] + bias[c];
                if constexpr (MODE == 2) {
                    v = fmaxf(v, 0.f);
                    ((u16*)outp)[(size_t)r * 1024 + c] = f2bf(v);
                } else {
                    ((float*)outp)[(size_t)r * 1024 + c] = v;
                }
            }
}

// ---------------------------------------------------------------------------
// Pass 1: partial[zg][n][m] = sum_{z in zg*16..+16} exp2(s'_znm) * km01(z,m)
// 1-D grid 1024, XCD-swizzled: XCD c owns one zg x 8 m-tiles.
// ---------------------------------------------------------------------------
__launch_bounds__(256)
__global__ void attn_pass1(const u16* __restrict__ Qh, const u16* __restrict__ Kh,
                           const float* __restrict__ km, float* __restrict__ partial)
{
    const int bid = blockIdx.x;
    const int mtzg = (bid & 7) * 8 + ((bid >> 3) & 7);   // cluster per XCD
    const int m0 = (mtzg & 15) * 64, zg = mtzg >> 4;
    const int n0 = (bid >> 6) * 64;

    __shared__ __align__(16) u16 lQ[2][64 * 64];
    __shared__ __align__(16) u16 lK[2][64 * 64];
    const int tid = threadIdx.x, lane = tid & 63, w = tid >> 6;
    const int frow = lane & 15, koct = lane >> 4;
    const int wn = (w >> 1) * 32, wm = (w & 1) * 32;
    f32x4 ssum[2][2] = {};

    auto stage = [&](int buf, int z) {
        #pragma unroll
        for (int i = 0; i < 2; i++) {
            int p = tid + i * 256;
            int row = p >> 3, sl = p & 7, ssl = sl ^ (row & 7);
            gload16(Qh + (size_t)(z * NSEQ + n0 + row) * 64 + ssl * 8, (char*)lQ[buf] + p * 16);
            gload16(Kh + (size_t)(z * NSEQ + m0 + row) * 64 + ssl * 8, (char*)lK[buf] + p * 16);
        }
    };

    const int z0 = zg * 16;
    stage(0, z0);
    __syncthreads();
    int buf = 0;
    for (int zi = 0; zi < 16; zi++) {
        const int z = z0 + zi;
        if (zi < 15) stage(buf ^ 1, z + 1);
        f32x4 km4[2];
        #pragma unroll
        for (int j = 0; j < 2; j++)
            km4[j] = *(const f32x4*)(km + z * NSEQ + m0 + wm + j * 16 + koct * 4);
        f32x4 s[2][2] = {};
        __builtin_amdgcn_s_setprio(1);
        #pragma unroll
        for (int ks = 0; ks < 2; ks++) {
            bf16x8 a[2], b2[2];
            #pragma unroll
            for (int i = 0; i < 2; i++) {
                int r = wn + i * 16 + frow;
                int sl = (ks * 4 + koct) ^ (r & 7);
                a[i] = *(const bf16x8*)((const char*)lQ[buf] + r * 128 + sl * 16);
            }
            #pragma unroll
            for (int j = 0; j < 2; j++) {
                int r = wm + j * 16 + frow;
                int sl = (ks * 4 + koct) ^ (r & 7);
                b2[j] = *(const bf16x8*)((const char*)lK[buf] + r * 128 + sl * 16);
            }
            #pragma unroll
            for (int i = 0; i < 2; i++)
                #pragma unroll
                for (int j = 0; j < 2; j++)
                    s[i][j] = __builtin_amdgcn_mfma_f32_16x16x32_bf16(b2[j], a[i], s[i][j], 0, 0, 0);
        }
        __builtin_amdgcn_s_setprio(0);
        #pragma unroll
        for (int j = 0; j < 2; j++)
            #pragma unroll
            for (int i = 0; i < 2; i++)
                #pragma unroll
                for (int q = 0; q < 4; q++)
                    ssum[i][j][q] += __builtin_amdgcn_exp2f(s[i][j][q]) * km4[j][q];
        __syncthreads();
        buf ^= 1;
    }
    #pragma unroll
    for (int i = 0; i < 2; i++)
        #pragma unroll
        for (int j = 0; j < 2; j++) {
            int ng = n0 + wn + i * 16 + frow;
            int mg = m0 + wm + j * 16 + koct * 4;
            *(f32x4*)(partial + (size_t)zg * 1048576 + (size_t)ng * NSEQ + mg) = ssum[i][j];
        }
}

// invS = 1 / (p0+p1+p2+p3)
__launch_bounds__(256)
__global__ void sum_inv(const float* __restrict__ p, float* __restrict__ invS) {
    int i = (blockIdx.x * 256 + threadIdx.x) * 4;
    float4 a = *(const float4*)(p + i);
    float4 b = *(const float4*)(p + 1048576 + i);
    float4 c = *(const float4*)(p + 2097152 + i);
    float4 d = *(const float4*)(p + 3145728 + i);
    float4 r;
    float s;
    s = a.x + b.x + c.x + d.x; r.x = s > 0.f ? 1.f / s : 0.f;
    s = a.y + b.y + c.y + d.y; r.y = s > 0.f ? 1.f / s : 0.f;
    s = a.z + b.z + c.z + d.z; r.z = s > 0.f ? 1.f / s : 0.f;
    s = a.w + b.w + c.w + d.w; r.w = s > 0.f ? 1.f / s : 0.f;
    *(float4*)(invS + i) = r;
}

// ---------------------------------------------------------------------------
// Pass 2: per z, out[z,n,:] = sum_m (exp2(s')*invS) V'[m,:]   (V' = V*km)
// 1-D grid 1024, XCD-swizzled: XCD c owns z in {8c..8c+7} (K/V L2-resident).
// ---------------------------------------------------------------------------
__launch_bounds__(256)
__global__ void attn_pass2(const u16* __restrict__ Qh, const u16* __restrict__ Kh,
                           const u16* __restrict__ Vt,
                           const float* __restrict__ qm, const float* __restrict__ invS,
                           const u8* __restrict__ pad, float* __restrict__ attn)
{
    const int bid = blockIdx.x;
    const int z  = (bid & 7) * 8 + ((bid >> 3) & 7);     // cluster per XCD
    const int n0 = (bid >> 6) * 64;

    __shared__ __align__(16) u16 lK[2][64 * 64];
    __shared__ __align__(16) u16 lV[2][64 * 64];   // Vt tile: [d][m]
    __shared__ __align__(16) u16 lP[64 * 64];
    const int tid = threadIdx.x, lane = tid & 63, w = tid >> 6;
    const int frow = lane & 15, koct = lane >> 4;
    const int hh = z >> 2, bb = z & 3;
    const int wrow = w * 16;
    const int nl_row = wrow + frow;
    const size_t inv_base = (size_t)(n0 + nl_row) * NSEQ;

    bf16x8 aq[2];
    #pragma unroll
    for (int ks = 0; ks < 2; ks++)
        aq[ks] = *(const bf16x8*)(Qh + (size_t)(z * NSEQ + n0 + nl_row) * 64 + ks * 32 + koct * 8);

    auto stage = [&](int buf, int m0) {
        #pragma unroll
        for (int i = 0; i < 2; i++) {
            int p = tid + i * 256;
            int row = p >> 3, sl = p & 7, ssl = sl ^ (row & 7);
            gload16(Kh + (size_t)(z * NSEQ + m0 + row) * 64 + ssl * 8, (char*)lK[buf] + p * 16);
            gload16(Vt + (size_t)z * 65536 + (size_t)row * 1024 + m0 + ssl * 8, (char*)lV[buf] + p * 16);
        }
    };

    f32x4 oacc[4] = {};
    f32x4 iv[4];
    #pragma unroll
    for (int j = 0; j < 4; j++)
        iv[j] = *(const f32x4*)(invS + inv_base + j * 16 + koct * 4);
    stage(0, 0);
    __syncthreads();
    int buf = 0;

    for (int mt = 0; mt < 16; mt++) {
        const int m0 = mt * 64;
        if (mt < 15) stage(buf ^ 1, m0 + 64);
        f32x4 ivn[4];
        if (mt < 15) {
            #pragma unroll
            for (int j = 0; j < 4; j++)
                ivn[j] = *(const f32x4*)(invS + inv_base + m0 + 64 + j * 16 + koct * 4);
        }
        f32x4 s[4] = {};
        __builtin_amdgcn_s_setprio(1);
        #pragma unroll
        for (int ks = 0; ks < 2; ks++) {
            bf16x8 kb[4];
            #pragma unroll
            for (int j = 0; j < 4; j++) {
                int r = j * 16 + frow;
                int sl = (ks * 4 + koct) ^ (r & 7);
                kb[j] = *(const bf16x8*)((const char*)lK[buf] + r * 128 + sl * 16);
            }
            #pragma unroll
            for (int j = 0; j < 4; j++)
                s[j] = __builtin_amdgcn_mfma_f32_16x16x32_bf16(kb[j], aq[ks], s[j], 0, 0, 0);
        }
        __builtin_amdgcn_s_setprio(0);
        #pragma unroll
        for (int j = 0; j < 4; j++) {
            float p0 = __builtin_amdgcn_exp2f(s[j][0]) * iv[j][0];
            float p1 = __builtin_amdgcn_exp2f(s[j][1]) * iv[j][1];
            float p2 = __builtin_amdgcn_exp2f(s[j][2]) * iv[j][2];
            float p3 = __builtin_amdgcn_exp2f(s[j][3]) * iv[j][3];
            uint2 pk;
            pk.x = cvt_pk_bf16(p0, p1);
            pk.y = cvt_pk_bf16(p2, p3);
            int slot = (j * 2 + (koct >> 1)) ^ (nl_row & 7);
            *(uint2*)((char*)lP + nl_row * 128 + slot * 16 + (koct & 1) * 8) = pk;
        }
        __builtin_amdgcn_s_setprio(1);
        #pragma unroll
        for (int ks = 0; ks < 2; ks++) {
            int sl = (ks * 4 + koct) ^ (nl_row & 7);
            bf16x8 pa = *(const bf16x8*)((const char*)lP + nl_row * 128 + sl * 16);
            bf16x8 vb[4];
            #pragma unroll
            for (int dj = 0; dj < 4; dj++) {
                int rr = dj * 16 + frow;
                int sv = (ks * 4 + koct) ^ (rr & 7);
                vb[dj] = *(const bf16x8*)((const char*)lV[buf] + rr * 128 + sv * 16);
            }
            #pragma unroll
            for (int dj = 0; dj < 4; dj++)
                oacc[dj] = __builtin_amdgcn_mfma_f32_16x16x32_bf16(pa, vb[dj], oacc[dj], 0, 0, 0);
        }
        __builtin_amdgcn_s_setprio(0);
        __syncthreads();
        buf ^= 1;
        #pragma unroll
        for (int j = 0; j < 4; j++) iv[j] = ivn[j];
    }

    #pragma unroll
    for (int q = 0; q < 4; q++) {
        int ns = n0 + wrow + koct * 4 + q;
        float f = qm[z * NSEQ + ns] * (pad[bb * NSEQ + ns] ? 0.f : 1.f);
        #pragma unroll
        for (int dj = 0; dj < 4; dj++) {
            int d = dj * 16 + frow;
            attn[(size_t)(bb * NSEQ + ns) * DMODEL + hh * 64 + d] = oacc[dj][q] * f;
        }
    }
}

// ---------------------------------------------------------------------------
// LayerNorm over last dim (1024), one block per row.
// ---------------------------------------------------------------------------
__launch_bounds__(256)
__global__ void ln_kernel(const float* __restrict__ A, const float* __restrict__ Bv,
                          const float* __restrict__ g, const float* __restrict__ beta,
                          const u8* __restrict__ pad, int mode,
                          float* __restrict__ out, u16* __restrict__ outb)
{
    const int row = blockIdx.x, tid = threadIdx.x;
    const int lane = tid & 63, wv = tid >> 6;
    const float valid = pad[row] ? 0.f : 1.f;
    __shared__ float red[4];

    float4 va = *(const float4*)(A + (size_t)row * 1024 + tid * 4);
    float4 vb = *(const float4*)(Bv + (size_t)row * 1024 + tid * 4);
    float v[4];
    if (mode == 0) {
        v[0] = va.x + vb.x; v[1] = va.y + vb.y; v[2] = va.z + vb.z; v[3] = va.w + vb.w;
    } else {
        v[0] = va.x * valid + vb.x; v[1] = va.y * valid + vb.y;
        v[2] = va.z * valid + vb.z; v[3] = va.w * valid + vb.w;
    }
    float s = v[0] + v[1] + v[2] + v[3];
    #pragma unroll
    for (int off = 32; off > 0; off >>= 1) s += __shfl_down(s, off, 64);
    if (lane == 0) red[wv] = s;
    __syncthreads();
    float mean = (red[0] + red[1] + red[2] + red[3]) * (1.f / 1024.f);
    float sq = 0.f;
    #pragma unroll
    for (int k = 0; k < 4; k++) { float d = v[k] - mean; sq += d * d; }
    __syncthreads();
    #pragma unroll
    for (int off = 32; off > 0; off >>= 1) sq += __shfl_down(sq, off, 64);
    if (lane == 0) red[wv] = sq;
    __syncthreads();
    float var = (red[0] + red[1] + red[2] + red[3]) * (1.f / 1024.f);
    float rstd = rsqrtf(var + 1e-5f);
    float osc = (mode == 0) ? 1.f : valid;
    #pragma unroll
    for (int k = 0; k < 4; k++) {
        int c = tid * 4 + k;
        float o = ((v[k] - mean) * rstd * g[c] + beta[c]) * osc;
        out[(size_t)row * 1024 + c] = o;
        if (outb) outb[(size_t)row * 1024 + c] = f2bf(o);
    }
}

// ---------------------------------------------------------------------------
extern "C" void kernel_launch(void* const* d_in, const int* in_sizes, int n_in,
                              void* d_out, int out_size, void* d_ws, size_t ws_size,
                              hipStream_t stream)
{
    const float* x   = (const float*)d_in[0];
    const u8*    pad = (const u8*)d_in[1];
    const float* Wq  = (const float*)d_in[2];
    const float* Wk  = (const float*)d_in[3];
    const float* Wv  = (const float*)d_in[4];
    const float* W1  = (const float*)d_in[5];
    const float* b1  = (const float*)d_in[6];
    const float* W2  = (const float*)d_in[7];
    const float* b2  = (const float*)d_in[8];
    const float* g1  = (const float*)d_in[9];
    const float* be1 = (const float*)d_in[10];
    const float* g2  = (const float*)d_in[11];
    const float* be2 = (const float*)d_in[12];
    float* out = (float*)d_out;

    // workspace (~99 MB)
    u16* xb   = (u16*)d_ws;
    u16* Wqb  = xb   + 4194304;
    u16* Wkb  = Wqb  + 1048576;
    u16* Wvb  = Wkb  + 1048576;
    u16* W1b  = Wvb  + 1048576;
    u16* W2b  = W1b  + 1048576;
    u16* Qh   = W2b  + 1048576;        // [z][n][dh]
    u16* Kh   = Qh   + 4194304;        // [z][n][dh]
    u16* Vt   = Kh   + 4194304;        // [z][dh][n]  (km applied by vt_km)
    u16* hb   = Vt   + 4194304;
    u16* ff1b = hb   + 4194304;
    float* km      = (float*)(ff1b + 4194304);
    float* qm      = km      + 65536;
    float* partial = qm      + 65536;           // 4M f32
    float* invS    = partial + 4194304;         // 1M f32
    float* h       = invS    + 1048576;         // 4M f32

    cvt_bf16<<<4096, 256, 0, stream>>>(x, xb);
    P5 p5;
    p5.in[0] = Wq; p5.in[1] = Wk; p5.in[2] = Wv; p5.in[3] = W1; p5.in[4] = W2;
    p5.out[0] = Wqb; p5.out[1] = Wkb; p5.out[2] = Wvb; p5.out[3] = W1b; p5.out[4] = W2b;
    cvt_bf16_5<<<5120, 256, 0, stream>>>(p5);

    // fused Q/K/V projections (Q scale folds 1/sqrt(DH)*log2e)
    gemm_qkv<<<dim3(48, 32), 256, 0, stream>>>(xb, Wqb, Wkb, Wvb, Qh, Kh, Vt);

    rowmask_bf<<<256, 256, 0, stream>>>(Kh, km);
    rowmask_bf<<<256, 256, 0, stream>>>(Qh, qm);
    vt_km<<<4096, 256, 0, stream>>>(Vt, km);

    attn_pass1<<<1024, 256, 0, stream>>>(Qh, Kh, km, partial);
    sum_inv<<<1024, 256, 0, stream>>>(partial, invS);
    attn_pass2<<<1024, 256, 0, stream>>>(Qh, Kh, Vt, qm, invS, pad, out);

    ln_kernel<<<4096, 256, 0, stream>>>(x, out, g1, be1, pad, 0, h, hb);

    gemm_bt<2><<<dim3(16, 32), 256, 0, stream>>>(hb,   W1b, b1, ff1b);
    gemm_bt<3><<<dim3(16, 32), 256, 0, stream>>>(ff1b, W2b, b2, out);

    ln_kernel<<<4096, 256, 0, stream>>>(out, h, g2, be2, pad, 1, out, nullptr);
}

// Round 7
// 200.236 us; speedup vs baseline: 11.7633x; 1.0122x over previous
//
#include <hip/hip_runtime.h>
#include <math.h>

typedef unsigned short u16;
typedef unsigned char  u8;
typedef unsigned int   u32;
typedef __attribute__((ext_vector_type(8))) short bf16x8;
typedef __attribute__((ext_vector_type(4))) float f32x4;

#define NSEQ   1024
#define DMODEL 1024
#define ZTOT   64
#define LOG2E  1.4426950408889634f

typedef const __attribute__((address_space(1))) void* gp1;
typedef __attribute__((address_space(3))) void* lp3;

__device__ __forceinline__ void gload16(const void* g, void* l) {
    __builtin_amdgcn_global_load_lds((gp1)g, (lp3)l, 16, 0, 0);
}

__device__ __forceinline__ u16 f2bf(float f) {
    u32 u = __builtin_bit_cast(u32, f);
    return (u16)((u + 0x7FFFu + ((u >> 16) & 1u)) >> 16);
}

// HW packed f32->bf16 (RNE), 2 values -> 1 dword
__device__ __forceinline__ u32 cvt_pk_bf16(float a, float b) {
    u32 r;
    asm("v_cvt_pk_bf16_f32 %0, %1, %2" : "=v"(r) : "v"(a), "v"(b));
    return r;
}

// ---------------------------------------------------------------------------
// fp32 -> bf16 elementwise
// ---------------------------------------------------------------------------
__launch_bounds__(256)
__global__ void cvt_bf16(const float* __restrict__ in, u16* __restrict__ out) {
    int i = (blockIdx.x * 256 + threadIdx.x) * 4;
    float4 v = *(const float4*)(in + i);
    uint2 o;
    o.x = cvt_pk_bf16(v.x, v.y);
    o.y = cvt_pk_bf16(v.z, v.w);
    *(uint2*)(out + i) = o;
}

struct P5 { const float* in[5]; u16* out[5]; };
__launch_bounds__(256)
__global__ void cvt_bf16_5(P5 p) {
    int which = blockIdx.x >> 10;
    int blk   = blockIdx.x & 1023;
    int i = (blk * 256 + threadIdx.x) * 4;
    float4 v = *(const float4*)(p.in[which] + i);
    uint2 o;
    o.x = cvt_pk_bf16(v.x, v.y);
    o.y = cvt_pk_bf16(v.z, v.w);
    *(uint2*)(p.out[which] + i) = o;
}

// sign(sum |row|) over 64 bf16 -> 0/1 ; grid 512: first half Kh->km, second Qh->qm
__launch_bounds__(256)
__global__ void rowmask2_bf(const u16* __restrict__ Kh, const u16* __restrict__ Qh,
                            float* __restrict__ km, float* __restrict__ qm) {
    int b = blockIdx.x;
    const u16* T = (b < 256) ? Kh : Qh;
    float* o = (b < 256) ? km : qm;
    int r = (b & 255) * 256 + threadIdx.x;
    const uint4* p = (const uint4*)(T + (size_t)r * 64);
    u32 acc = 0;
    #pragma unroll
    for (int i = 0; i < 8; i++) {
        uint4 q = p[i];
        acc |= (q.x | q.y | q.z | q.w) & 0x7fff7fffu;
    }
    o[r] = acc ? 1.f : 0.f;
}

// Vt[z][dh][tok] &= (km[z][tok] != 0)
__launch_bounds__(256)
__global__ void vt_km(u16* __restrict__ Vt, const float* __restrict__ km) {
    int idx = blockIdx.x * 256 + threadIdx.x;  // uint4 index (8 bf16)
    int e0 = idx * 8;
    int z = e0 >> 16;
    int tok = e0 & 1023;
    float4 ka = *(const float4*)(km + z * 1024 + tok);
    float4 kb = *(const float4*)(km + z * 1024 + tok + 4);
    uint4 v = *(uint4*)(Vt + e0);
    u32 m;
    m = (ka.x != 0.f ? 0x0000FFFFu : 0u) | (ka.y != 0.f ? 0xFFFF0000u : 0u); v.x &= m;
    m = (ka.z != 0.f ? 0x0000FFFFu : 0u) | (ka.w != 0.f ? 0xFFFF0000u : 0u); v.y &= m;
    m = (kb.x != 0.f ? 0x0000FFFFu : 0u) | (kb.y != 0.f ? 0xFFFF0000u : 0u); v.z &= m;
    m = (kb.z != 0.f ? 0x0000FFFFu : 0u) | (kb.w != 0.f ? 0xFFFF0000u : 0u); v.w &= m;
    *(uint4*)(Vt + e0) = v;
}

// ---------------------------------------------------------------------------
// Fused QKV projection GEMM, m97 structure: BM=BN=128, BK=32, 4 waves (2x2,
// each 64x64), double-buffered gload_lds staging. grid (24, 32): bx>>3
// selects {Q, K, V}; col0 = (bx&7)*128.
// Q: head-major bf16 * (0.125*log2e). K: head-major. V: transposed [z][dh][tok].
// ---------------------------------------------------------------------------
__launch_bounds__(256)
__global__ void gemm_qkv(const u16* __restrict__ A,
                         const u16* __restrict__ Wq, const u16* __restrict__ Wk,
                         const u16* __restrict__ Wv,
                         u16* __restrict__ Qh, u16* __restrict__ Kh, u16* __restrict__ Vt)
{
    __shared__ __align__(16) u16 lA[2][128 * 32];
    __shared__ __align__(16) u16 lB[2][128 * 32];
    const int tid = threadIdx.x, lane = tid & 63, w = tid >> 6;
    const int frow = lane & 15, koct = lane >> 4;
    const int sel = blockIdx.x >> 3;
    const int col0 = (blockIdx.x & 7) * 128, row0 = blockIdx.y * 128;
    const u16* B = (sel == 0) ? Wq : (sel == 1) ? Wk : Wv;
    const int wrow = (w >> 1) * 64, wcol = (w & 1) * 64;
    f32x4 acc[4][4] = {};

    // A/B tiles: 128 rows x 32 k = 8KB each = 512 x 16B chunks, 2/thread each
    auto stage = [&](int buf, int k0) {
        #pragma unroll
        for (int i = 0; i < 2; i++) {
            int p = tid + i * 256;
            int row = p >> 2, sl = p & 3, ssl = sl ^ ((row >> 1) & 3);
            gload16(A + (size_t)(row0 + row) * 1024 + k0 + ssl * 8, (char*)lA[buf] + p * 16);
        }
        #pragma unroll
        for (int i = 0; i < 2; i++) {
            int p = tid + i * 256;
            int row = p >> 2, sl = p & 3, ssl = sl ^ ((row >> 1) & 3);
            gload16(B + (size_t)(col0 + row) * 1024 + k0 + ssl * 8, (char*)lB[buf] + p * 16);
        }
    };

    stage(0, 0);
    __syncthreads();
    int buf = 0;
    for (int k0 = 0; k0 < 1024; k0 += 32) {
        if (k0 + 32 < 1024) stage(buf ^ 1, k0 + 32);
        __builtin_amdgcn_s_setprio(1);
        bf16x8 af[4], bf[4];
        #pragma unroll
        for (int i = 0; i < 4; i++) {
            int r = wrow + i * 16 + frow;
            int sl = koct ^ ((r >> 1) & 3);
            af[i] = *(const bf16x8*)((const char*)lA[buf] + r * 64 + sl * 16);
        }
        #pragma unroll
        for (int j = 0; j < 4; j++) {
            int r = wcol + j * 16 + frow;
            int sl = koct ^ ((r >> 1) & 3);
            bf[j] = *(const bf16x8*)((const char*)lB[buf] + r * 64 + sl * 16);
        }
        #pragma unroll
        for (int i = 0; i < 4; i++)
            #pragma unroll
            for (int j = 0; j < 4; j++)
                acc[i][j] = __builtin_amdgcn_mfma_f32_16x16x32_bf16(af[i], bf[j], acc[i][j], 0, 0, 0);
        __builtin_amdgcn_s_setprio(0);
        __syncthreads();
        buf ^= 1;
    }

    if (sel < 2) {
        const float scale = (sel == 0) ? 0.125f * LOG2E : 1.0f;
        u16* outp = (sel == 0) ? Qh : Kh;
        #pragma unroll
        for (int i = 0; i < 4; i++)
            #pragma unroll
            for (int j = 0; j < 4; j++)
                #pragma unroll
                for (int q = 0; q < 4; q++) {
                    int r = row0 + wrow + i * 16 + koct * 4 + q;
                    int c = col0 + wcol + j * 16 + frow;
                    float v = acc[i][j][q] * scale;
                    outp[(size_t)((c >> 6) * 4 + (r >> 10)) * 65536 +
                         (size_t)(r & 1023) * 64 + (c & 63)] = f2bf(v);
                }
    } else {
        // Vt[z][dh][tok]: tokens are q-consecutive -> 8B packed stores
        #pragma unroll
        for (int i = 0; i < 4; i++) {
            int r0 = row0 + wrow + i * 16 + koct * 4;   // token base (mult of 4)
            #pragma unroll
            for (int j = 0; j < 4; j++) {
                int c = col0 + wcol + j * 16 + frow;    // channel
                int z = (c >> 6) * 4 + (r0 >> 10);
                uint2 pk;
                pk.x = cvt_pk_bf16(acc[i][j][0], acc[i][j][1]);
                pk.y = cvt_pk_bf16(acc[i][j][2], acc[i][j][3]);
                *(uint2*)(Vt + (size_t)z * 65536 + (size_t)(c & 63) * 1024 + (r0 & 1023)) = pk;
            }
        }
    }
}

// ---------------------------------------------------------------------------
// bf16 MFMA GEMM for FFN. D[r,c] = sum_k A[r,k]*B[c,k]  (K = 1024)
// BM=128, BN=64, BK=64, dbuf. MODE 2: +bias+relu bf16. MODE 3: +bias f32.
// ---------------------------------------------------------------------------
template <int MODE>
__launch_bounds__(256)
__global__ void gemm_bt(const u16* __restrict__ A, const u16* __restrict__ B,
                        const float* __restrict__ bias, void* __restrict__ outp)
{
    __shared__ __align__(16) u16 lA[2][128 * 64];
    __shared__ __align__(16) u16 lB[2][64 * 64];
    const int tid = threadIdx.x, lane = tid & 63, w = tid >> 6;
    const int frow = lane & 15, koct = lane >> 4;
    const int col0 = blockIdx.x * 64, row0 = blockIdx.y * 128;
    const int wrow = (w >> 1) * 64, wcol = (w & 1) * 32;
    f32x4 acc[4][2] = {};

    auto stage = [&](int buf, int k0) {
        #pragma unroll
        for (int i = 0; i < 4; i++) {
            int p = tid + i * 256;
            int row = p >> 3, sl = p & 7, ssl = sl ^ (row & 7);
            gload16(A + (size_t)(row0 + row) * 1024 + k0 + ssl * 8, (char*)lA[buf] + p * 16);
        }
        #pragma unroll
        for (int i = 0; i < 2; i++) {
            int p = tid + i * 256;
            int row = p >> 3, sl = p & 7, ssl = sl ^ (row & 7);
            gload16(B + (size_t)(col0 + row) * 1024 + k0 + ssl * 8, (char*)lB[buf] + p * 16);
        }
    };

    stage(0, 0);
    __syncthreads();
    int buf = 0;
    for (int k0 = 0; k0 < 1024; k0 += 64) {
        if (k0 + 64 < 1024) stage(buf ^ 1, k0 + 64);
        __builtin_amdgcn_s_setprio(1);
        #pragma unroll
        for (int ks = 0; ks < 2; ks++) {
            bf16x8 af[4], bf2[2];
            #pragma unroll
            for (int i = 0; i < 4; i++) {
                int r = wrow + i * 16 + frow;
                int sl = (ks * 4 + koct) ^ (r & 7);
                af[i] = *(const bf16x8*)((const char*)lA[buf] + r * 128 + sl * 16);
            }
            #pragma unroll
            for (int j = 0; j < 2; j++) {
                int r = wcol + j * 16 + frow;
                int sl = (ks * 4 + koct) ^ (r & 7);
                bf2[j] = *(const bf16x8*)((const char*)lB[buf] + r * 128 + sl * 16);
            }
            #pragma unroll
            for (int i = 0; i < 4; i++)
                #pragma unroll
                for (int j = 0; j < 2; j++)
                    acc[i][j] = __builtin_amdgcn_mfma_f32_16x16x32_bf16(af[i], bf2[j], acc[i][j], 0, 0, 0);
        }
        __builtin_amdgcn_s_setprio(0);
        __syncthreads();
        buf ^= 1;
    }

    #pragma unroll
    for (int i = 0; i < 4; i++)
        #pragma unroll
        for (int j = 0; j < 2; j++)
            #pragma unroll
            for (int q = 0; q < 4; q++) {
                int r = row0 + wrow + i * 16 + koct * 4 + q;
                int c = col0 + wcol + j * 16 + frow;
                float v = acc[i][j][q] + bias[c];
                if constexpr (MODE == 2) {
                    v = fmaxf(v, 0.f);
                    ((u16*)outp)[(size_t)r * 1024 + c] = f2bf(v);
                } else {
                    ((float*)outp)[(size_t)r * 1024 + c] = v;
                }
            }
}

// ---------------------------------------------------------------------------
// Pass 1: partial[zg][n][m] = sum_{z in zg*16..+16} exp2(s'_znm) * km01(z,m)
// 1-D grid 1024, XCD-swizzled: XCD c owns one zg x 8 m-tiles.
// ---------------------------------------------------------------------------
__launch_bounds__(256)
__global__ void attn_pass1(const u16* __restrict__ Qh, const u16* __restrict__ Kh,
                           const float* __restrict__ km, float* __restrict__ partial)
{
    const int bid = blockIdx.x;
    const int mtzg = (bid & 7) * 8 + ((bid >> 3) & 7);   // cluster per XCD
    const int m0 = (mtzg & 15) * 64, zg = mtzg >> 4;
    const int n0 = (bid >> 6) * 64;

    __shared__ __align__(16) u16 lQ[2][64 * 64];
    __shared__ __align__(16) u16 lK[2][64 * 64];
    const int tid = threadIdx.x, lane = tid & 63, w = tid >> 6;
    const int frow = lane & 15, koct = lane >> 4;
    const int wn = (w >> 1) * 32, wm = (w & 1) * 32;
    f32x4 ssum[2][2] = {};

    auto stage = [&](int buf, int z) {
        #pragma unroll
        for (int i = 0; i < 2; i++) {
            int p = tid + i * 256;
            int row = p >> 3, sl = p & 7, ssl = sl ^ (row & 7);
            gload16(Qh + (size_t)(z * NSEQ + n0 + row) * 64 + ssl * 8, (char*)lQ[buf] + p * 16);
            gload16(Kh + (size_t)(z * NSEQ + m0 + row) * 64 + ssl * 8, (char*)lK[buf] + p * 16);
        }
    };

    const int z0 = zg * 16;
    stage(0, z0);
    __syncthreads();
    int buf = 0;
    for (int zi = 0; zi < 16; zi++) {
        const int z = z0 + zi;
        if (zi < 15) stage(buf ^ 1, z + 1);
        f32x4 km4[2];
        #pragma unroll
        for (int j = 0; j < 2; j++)
            km4[j] = *(const f32x4*)(km + z * NSEQ + m0 + wm + j * 16 + koct * 4);
        f32x4 s[2][2] = {};
        __builtin_amdgcn_s_setprio(1);
        #pragma unroll
        for (int ks = 0; ks < 2; ks++) {
            bf16x8 a[2], b2[2];
            #pragma unroll
            for (int i = 0; i < 2; i++) {
                int r = wn + i * 16 + frow;
                int sl = (ks * 4 + koct) ^ (r & 7);
                a[i] = *(const bf16x8*)((const char*)lQ[buf] + r * 128 + sl * 16);
            }
            #pragma unroll
            for (int j = 0; j < 2; j++) {
                int r = wm + j * 16 + frow;
                int sl = (ks * 4 + koct) ^ (r & 7);
                b2[j] = *(const bf16x8*)((const char*)lK[buf] + r * 128 + sl * 16);
            }
            #pragma unroll
            for (int i = 0; i < 2; i++)
                #pragma unroll
                for (int j = 0; j < 2; j++)
                    s[i][j] = __builtin_amdgcn_mfma_f32_16x16x32_bf16(b2[j], a[i], s[i][j], 0, 0, 0);
        }
        __builtin_amdgcn_s_setprio(0);
        #pragma unroll
        for (int j = 0; j < 2; j++)
            #pragma unroll
            for (int i = 0; i < 2; i++)
                #pragma unroll
                for (int q = 0; q < 4; q++)
                    ssum[i][j][q] += __builtin_amdgcn_exp2f(s[i][j][q]) * km4[j][q];
        __syncthreads();
        buf ^= 1;
    }
    #pragma unroll
    for (int i = 0; i < 2; i++)
        #pragma unroll
        for (int j = 0; j < 2; j++) {
            int ng = n0 + wn + i * 16 + frow;
            int mg = m0 + wm + j * 16 + koct * 4;
            *(f32x4*)(partial + (size_t)zg * 1048576 + (size_t)ng * NSEQ + mg) = ssum[i][j];
        }
}

// invS = 1 / (p0+p1+p2+p3)
__launch_bounds__(256)
__global__ void sum_inv(const float* __restrict__ p, float* __restrict__ invS) {
    int i = (blockIdx.x * 256 + threadIdx.x) * 4;
    float4 a = *(const float4*)(p + i);
    float4 b = *(const float4*)(p + 1048576 + i);
    float4 c = *(const float4*)(p + 2097152 + i);
    float4 d = *(const float4*)(p + 3145728 + i);
    float4 r;
    float s;
    s = a.x + b.x + c.x + d.x; r.x = s > 0.f ? 1.f / s : 0.f;
    s = a.y + b.y + c.y + d.y; r.y = s > 0.f ? 1.f / s : 0.f;
    s = a.z + b.z + c.z + d.z; r.z = s > 0.f ? 1.f / s : 0.f;
    s = a.w + b.w + c.w + d.w; r.w = s > 0.f ? 1.f / s : 0.f;
    *(float4*)(invS + i) = r;
}

// ---------------------------------------------------------------------------
// Pass 2: per z, out[z,n,:] = sum_m (exp2(s')*invS) V'[m,:]   (V' = V*km)
// 1-D grid 1024, XCD-swizzled: XCD c owns z in {8c..8c+7} (K/V L2-resident).
// ---------------------------------------------------------------------------
__launch_bounds__(256)
__global__ void attn_pass2(const u16* __restrict__ Qh, const u16* __restrict__ Kh,
                           const u16* __restrict__ Vt,
                           const float* __restrict__ qm, const float* __restrict__ invS,
                           const u8* __restrict__ pad, float* __restrict__ attn)
{
    const int bid = blockIdx.x;
    const int z  = (bid & 7) * 8 + ((bid >> 3) & 7);     // cluster per XCD
    const int n0 = (bid >> 6) * 64;

    __shared__ __align__(16) u16 lK[2][64 * 64];
    __shared__ __align__(16) u16 lV[2][64 * 64];   // Vt tile: [d][m]
    __shared__ __align__(16) u16 lP[64 * 64];
    const int tid = threadIdx.x, lane = tid & 63, w = tid >> 6;
    const int frow = lane & 15, koct = lane >> 4;
    const int hh = z >> 2, bb = z & 3;
    const int wrow = w * 16;
    const int nl_row = wrow + frow;
    const size_t inv_base = (size_t)(n0 + nl_row) * NSEQ;

    bf16x8 aq[2];
    #pragma unroll
    for (int ks = 0; ks < 2; ks++)
        aq[ks] = *(const bf16x8*)(Qh + (size_t)(z * NSEQ + n0 + nl_row) * 64 + ks * 32 + koct * 8);

    auto stage = [&](int buf, int m0) {
        #pragma unroll
        for (int i = 0; i < 2; i++) {
            int p = tid + i * 256;
            int row = p >> 3, sl = p & 7, ssl = sl ^ (row & 7);
            gload16(Kh + (size_t)(z * NSEQ + m0 + row) * 64 + ssl * 8, (char*)lK[buf] + p * 16);
            gload16(Vt + (size_t)z * 65536 + (size_t)row * 1024 + m0 + ssl * 8, (char*)lV[buf] + p * 16);
        }
    };

    f32x4 oacc[4] = {};
    f32x4 iv[4];
    #pragma unroll
    for (int j = 0; j < 4; j++)
        iv[j] = *(const f32x4*)(invS + inv_base + j * 16 + koct * 4);
    stage(0, 0);
    __syncthreads();
    int buf = 0;

    for (int mt = 0; mt < 16; mt++) {
        const int m0 = mt * 64;
        if (mt < 15) stage(buf ^ 1, m0 + 64);
        f32x4 ivn[4];
        if (mt < 15) {
            #pragma unroll
            for (int j = 0; j < 4; j++)
                ivn[j] = *(const f32x4*)(invS + inv_base + m0 + 64 + j * 16 + koct * 4);
        }
        f32x4 s[4] = {};
        __builtin_amdgcn_s_setprio(1);
        #pragma unroll
        for (int ks = 0; ks < 2; ks++) {
            bf16x8 kb[4];
            #pragma unroll
            for (int j = 0; j < 4; j++) {
                int r = j * 16 + frow;
                int sl = (ks * 4 + koct) ^ (r & 7);
                kb[j] = *(const bf16x8*)((const char*)lK[buf] + r * 128 + sl * 16);
            }
            #pragma unroll
            for (int j = 0; j < 4; j++)
                s[j] = __builtin_amdgcn_mfma_f32_16x16x32_bf16(kb[j], aq[ks], s[j], 0, 0, 0);
        }
        __builtin_amdgcn_s_setprio(0);
        #pragma unroll
        for (int j = 0; j < 4; j++) {
            float p0 = __builtin_amdgcn_exp2f(s[j][0]) * iv[j][0];
            float p1 = __builtin_amdgcn_exp2f(s[j][1]) * iv[j][1];
            float p2 = __builtin_amdgcn_exp2f(s[j][2]) * iv[j][2];
            float p3 = __builtin_amdgcn_exp2f(s[j][3]) * iv[j][3];
            uint2 pk;
            pk.x = cvt_pk_bf16(p0, p1);
            pk.y = cvt_pk_bf16(p2, p3);
            int slot = (j * 2 + (koct >> 1)) ^ (nl_row & 7);
            *(uint2*)((char*)lP + nl_row * 128 + slot * 16 + (koct & 1) * 8) = pk;
        }
        __builtin_amdgcn_s_setprio(1);
        #pragma unroll
        for (int ks = 0; ks < 2; ks++) {
            int sl = (ks * 4 + koct) ^ (nl_row & 7);
            bf16x8 pa = *(const bf16x8*)((const char*)lP + nl_row * 128 + sl * 16);
            bf16x8 vb[4];
            #pragma unroll
            for (int dj = 0; dj < 4; dj++) {
                int rr = dj * 16 + frow;
                int sv = (ks * 4 + koct) ^ (rr & 7);
                vb[dj] = *(const bf16x8*)((const char*)lV[buf] + rr * 128 + sv * 16);
            }
            #pragma unroll
            for (int dj = 0; dj < 4; dj++)
                oacc[dj] = __builtin_amdgcn_mfma_f32_16x16x32_bf16(pa, vb[dj], oacc[dj], 0, 0, 0);
        }
        __builtin_amdgcn_s_setprio(0);
        __syncthreads();
        buf ^= 1;
        #pragma unroll
        for (int j = 0; j < 4; j++) iv[j] = ivn[j];
    }

    #pragma unroll
    for (int q = 0; q < 4; q++) {
        int ns = n0 + wrow + koct * 4 + q;
        float f = qm[z * NSEQ + ns] * (pad[bb * NSEQ + ns] ? 0.f : 1.f);
        #pragma unroll
        for (int dj = 0; dj < 4; dj++) {
            int d = dj * 16 + frow;
            attn[(size_t)(bb * NSEQ + ns) * DMODEL + hh * 64 + d] = oacc[dj][q] * f;
        }
    }
}

// ---------------------------------------------------------------------------
// LayerNorm over last dim (1024), one block per row.
// ---------------------------------------------------------------------------
__launch_bounds__(256)
__global__ void ln_kernel(const float* __restrict__ A, const float* __restrict__ Bv,
                          const float* __restrict__ g, const float* __restrict__ beta,
                          const u8* __restrict__ pad, int mode,
                          float* __restrict__ out, u16* __restrict__ outb)
{
    const int row = blockIdx.x, tid = threadIdx.x;
    const int lane = tid & 63, wv = tid >> 6;
    const float valid = pad[row] ? 0.f : 1.f;
    __shared__ float red[4];

    float4 va = *(const float4*)(A + (size_t)row * 1024 + tid * 4);
    float4 vb = *(const float4*)(Bv + (size_t)row * 1024 + tid * 4);
    float v[4];
    if (mode == 0) {
        v[0] = va.x + vb.x; v[1] = va.y + vb.y; v[2] = va.z + vb.z; v[3] = va.w + vb.w;
    } else {
        v[0] = va.x * valid + vb.x; v[1] = va.y * valid + vb.y;
        v[2] = va.z * valid + vb.z; v[3] = va.w * valid + vb.w;
    }
    float s = v[0] + v[1] + v[2] + v[3];
    #pragma unroll
    for (int off = 32; off > 0; off >>= 1) s += __shfl_down(s, off, 64);
    if (lane == 0) red[wv] = s;
    __syncthreads();
    float mean = (red[0] + red[1] + red[2] + red[3]) * (1.f / 1024.f);
    float sq = 0.f;
    #pragma unroll
    for (int k = 0; k < 4; k++) { float d = v[k] - mean; sq += d * d; }
    __syncthreads();
    #pragma unroll
    for (int off = 32; off > 0; off >>= 1) sq += __shfl_down(sq, off, 64);
    if (lane == 0) red[wv] = sq;
    __syncthreads();
    float var = (red[0] + red[1] + red[2] + red[3]) * (1.f / 1024.f);
    float rstd = rsqrtf(var + 1e-5f);
    float osc = (mode == 0) ? 1.f : valid;
    #pragma unroll
    for (int k = 0; k < 4; k++) {
        int c = tid * 4 + k;
        float o = ((v[k] - mean) * rstd * g[c] + beta[c]) * osc;
        out[(size_t)row * 1024 + c] = o;
        if (outb) outb[(size_t)row * 1024 + c] = f2bf(o);
    }
}

// ---------------------------------------------------------------------------
extern "C" void kernel_launch(void* const* d_in, const int* in_sizes, int n_in,
                              void* d_out, int out_size, void* d_ws, size_t ws_size,
                              hipStream_t stream)
{
    const float* x   = (const float*)d_in[0];
    const u8*    pad = (const u8*)d_in[1];
    const float* Wq  = (const float*)d_in[2];
    const float* Wk  = (const float*)d_in[3];
    const float* Wv  = (const float*)d_in[4];
    const float* W1  = (const float*)d_in[5];
    const float* b1  = (const float*)d_in[6];
    const float* W2  = (const float*)d_in[7];
    const float* b2  = (const float*)d_in[8];
    const float* g1  = (const float*)d_in[9];
    const float* be1 = (const float*)d_in[10];
    const float* g2  = (const float*)d_in[11];
    const float* be2 = (const float*)d_in[12];
    float* out = (float*)d_out;

    // workspace (~99 MB)
    u16* xb   = (u16*)d_ws;
    u16* Wqb  = xb   + 4194304;
    u16* Wkb  = Wqb  + 1048576;
    u16* Wvb  = Wkb  + 1048576;
    u16* W1b  = Wvb  + 1048576;
    u16* W2b  = W1b  + 1048576;
    u16* Qh   = W2b  + 1048576;        // [z][n][dh]
    u16* Kh   = Qh   + 4194304;        // [z][n][dh]
    u16* Vt   = Kh   + 4194304;        // [z][dh][n]  (km applied by vt_km)
    u16* hb   = Vt   + 4194304;
    u16* ff1b = hb   + 4194304;
    float* km      = (float*)(ff1b + 4194304);
    float* qm      = km      + 65536;
    float* partial = qm      + 65536;           // 4M f32
    float* invS    = partial + 4194304;         // 1M f32
    float* h       = invS    + 1048576;         // 4M f32

    cvt_bf16<<<4096, 256, 0, stream>>>(x, xb);
    P5 p5;
    p5.in[0] = Wq; p5.in[1] = Wk; p5.in[2] = Wv; p5.in[3] = W1; p5.in[4] = W2;
    p5.out[0] = Wqb; p5.out[1] = Wkb; p5.out[2] = Wvb; p5.out[3] = W1b; p5.out[4] = W2b;
    cvt_bf16_5<<<5120, 256, 0, stream>>>(p5);

    // fused Q/K/V projections, m97-structure 128x128 tiles
    gemm_qkv<<<dim3(24, 32), 256, 0, stream>>>(xb, Wqb, Wkb, Wvb, Qh, Kh, Vt);

    rowmask2_bf<<<512, 256, 0, stream>>>(Kh, Qh, km, qm);
    vt_km<<<4096, 256, 0, stream>>>(Vt, km);

    attn_pass1<<<1024, 256, 0, stream>>>(Qh, Kh, km, partial);
    sum_inv<<<1024, 256, 0, stream>>>(partial, invS);
    attn_pass2<<<1024, 256, 0, stream>>>(Qh, Kh, Vt, qm, invS, pad, out);

    ln_kernel<<<4096, 256, 0, stream>>>(x, out, g1, be1, pad, 0, h, hb);

    gemm_bt<2><<<dim3(16, 32), 256, 0, stream>>>(hb,   W1b, b1, ff1b);
    gemm_bt<3><<<dim3(16, 32), 256, 0, stream>>>(ff1b, W2b, b2, out);

    ln_kernel<<<4096, 256, 0, stream>>>(out, h, g2, be2, pad, 1, out, nullptr);
}